// Round 2
// baseline (2168.251 us; speedup 1.0000x reference)
//
#include <hip/hip_runtime.h>
#include <stdint.h>

#define BB 4096
#define JJ 17
#define CC 512

typedef unsigned short u16;
typedef __bf16 bf16x8 __attribute__((ext_vector_type(8)));
typedef float  f32x4  __attribute__((ext_vector_type(4)));

__device__ __forceinline__ float bf2f(u16 u){ return __uint_as_float(((uint32_t)u)<<16); }
__device__ __forceinline__ u16 f2bf(float f){
  uint32_t u = __float_as_uint(f);
  u += 0x7fffu + ((u>>16)&1u);           // round-to-nearest-even
  return (u16)(u>>16);
}
__device__ __forceinline__ float gelu_f(float x){
  return 0.5f*x*(1.f+erff(x*0.70710678118654752f));
}
__device__ __forceinline__ void gll16(const void* g, void* l){
  __builtin_amdgcn_global_load_lds(
      (const __attribute__((address_space(1))) void*)g,
      (__attribute__((address_space(3))) void*)l, 16, 0, 0);
}

// ---------------- weight f32 -> bf16 convert ----------------
__global__ void k_cvt(const float* __restrict__ in, u16* __restrict__ out, int n){
  int i = blockIdx.x*blockDim.x + threadIdx.x;
  if (i < n) out[i] = f2bf(in[i]);
}

// ---------------- pre: LN(over J) + dwconv + GN1 + gelu ----------------
__global__ __launch_bounds__(512) void k_pre(
    const float* __restrict__ x, int b0,
    const float* __restrict__ n1w, const float* __restrict__ n1b,
    const float* __restrict__ dww, const float* __restrict__ dwb,
    const float* __restrict__ gn1w, const float* __restrict__ gn1b,
    u16* __restrict__ xc, u16* __restrict__ hgn)
{
  int b = blockIdx.x, c = threadIdx.x;
  const float* xp = x + (size_t)(b0+b)*JJ*CC + c;
  float v[JJ]; float s = 0.f;
  #pragma unroll
  for (int j=0;j<JJ;j++){ v[j] = xp[(size_t)j*CC]; s += v[j]; }
  float mn = s*(1.f/JJ); float var = 0.f;
  #pragma unroll
  for (int j=0;j<JJ;j++){ float d=v[j]-mn; var += d*d; }
  float rr = rsqrtf(var*(1.f/JJ)+1e-5f);
  float xcv[JJ];
  #pragma unroll
  for (int j=0;j<JJ;j++) xcv[j] = (v[j]-mn)*rr*n1w[j] + n1b[j];
  u16* xo = xc + (size_t)b*JJ*CC + c;
  #pragma unroll
  for (int j=0;j<JJ;j++) xo[(size_t)j*CC] = f2bf(xcv[j]);
  // depthwise conv (K=3, zero pad, correlation per XLA semantics)
  float w0=dww[c*3+0], w1=dww[c*3+1], w2=dww[c*3+2], db=dwb[c];
  float h[JJ];
  #pragma unroll
  for (int j=0;j<JJ;j++){
    float a = db + w1*xcv[j];
    if (j>0)    a += w0*xcv[j-1];
    if (j<JJ-1) a += w2*xcv[j+1];
    h[j] = a;
  }
  // GroupNorm: group = c/64 == wave id (blockDim=512)
  float ss=0.f, sq=0.f;
  #pragma unroll
  for (int j=0;j<JJ;j++){ ss += h[j]; sq += h[j]*h[j]; }
  for (int off=32; off; off>>=1){ ss += __shfl_xor(ss,off); sq += __shfl_xor(sq,off); }
  float gm = ss*(1.f/(64.f*JJ));
  float gr = rsqrtf(sq*(1.f/(64.f*JJ)) - gm*gm + 1e-5f);
  float gw = gn1w[c], gb = gn1b[c];
  u16* ho = hgn + (size_t)b*JJ*CC + c;
  #pragma unroll
  for (int j=0;j<JJ;j++){
    float t = (h[j]-gm)*gr*gw + gb;
    ho[(size_t)j*CC] = f2bf(gelu_f(t));
  }
}

// ---------------- MFMA GEMM: out[M,N] = A[M,K] @ W[N,K]^T (+bias)(+adds)(+gelu) ----------------
template<int DO_GELU, int DO_ADD>
__global__ __launch_bounds__(256) void gemm_bt(
    const u16* __restrict__ A, const u16* __restrict__ W, const float* __restrict__ bias,
    u16* __restrict__ out, const u16* __restrict__ add0, const u16* __restrict__ add1,
    int M, int N, int K)
{
  __shared__ __align__(16) u16 As[128*32];
  __shared__ __align__(16) u16 Bs[128*32];
  const int tid = threadIdx.x;
  const int wave = tid>>6, lane = tid&63;
  const int m0 = blockIdx.y*128, n0 = blockIdx.x*128;
  const int wm = (wave>>1)*64, wn = (wave&1)*64;
  f32x4 acc[4][4];
  const f32x4 z = {0.f,0.f,0.f,0.f};
  #pragma unroll
  for (int i=0;i<4;i++)
    #pragma unroll
    for (int j=0;j<4;j++) acc[i][j]=z;

  const u16* gA = A + (size_t)(m0 + (tid>>2))*K + (tid&3)*8;
  const u16* gB = W + (size_t)(n0 + (tid>>2))*K + (tid&3)*8;
  u16* lA = As + wave*512;   // wave-uniform LDS base (bytes: wave*1024)
  u16* lB = Bs + wave*512;
  const size_t r64 = (size_t)64*K;
  const int lr = lane&15, kg = (lane>>4)*8;

  for (int kk=0; kk<K; kk+=32){
    gll16(gA+kk,      lA);
    gll16(gA+kk+r64,  lA+2048);
    gll16(gB+kk,      lB);
    gll16(gB+kk+r64,  lB+2048);
    asm volatile("s_waitcnt vmcnt(0)" ::: "memory");
    __syncthreads();
    bf16x8 av[4], bv[4];
    #pragma unroll
    for (int i=0;i<4;i++) av[i] = *(const bf16x8*)&As[(wm+i*16+lr)*32 + kg];
    #pragma unroll
    for (int j=0;j<4;j++) bv[j] = *(const bf16x8*)&Bs[(wn+j*16+lr)*32 + kg];
    #pragma unroll
    for (int i=0;i<4;i++)
      #pragma unroll
      for (int j=0;j<4;j++)
        acc[i][j] = __builtin_amdgcn_mfma_f32_16x16x32_bf16(av[i], bv[j], acc[i][j], 0,0,0);
    __syncthreads();
  }

  const int rbase = (lane>>4)*4;
  #pragma unroll
  for (int i=0;i<4;i++){
    #pragma unroll
    for (int j=0;j<4;j++){
      const int col  = n0 + wn + j*16 + lr;
      const int row0 = m0 + wm + i*16 + rbase;
      const float bvl = bias[col];
      #pragma unroll
      for (int r=0;r<4;r++){
        size_t idx = (size_t)(row0+r)*N + col;
        float v = acc[i][j][r] + bvl;
        if (DO_ADD)  v += bf2f(add0[idx]) + bf2f(add1[idx]);
        if (DO_GELU) v = gelu_f(v);
        out[idx] = f2bf(v);
      }
    }
  }
}

// ---------------- adj contraction: xg[(b,w),c] = sum_{k,v} G[(b,v),k*512+c]*adj[k,v,w] ----------------
__global__ __launch_bounds__(512) void k_gcn(const u16* __restrict__ G, const float* __restrict__ adj,
                                             u16* __restrict__ xg){
  __shared__ float adj_l[3*17*17];
  int b = blockIdx.x, c = threadIdx.x;
  for (int i=c;i<867;i+=512) adj_l[i]=adj[i];
  __syncthreads();
  float y[3][JJ];
  const u16* gp = G + (size_t)b*JJ*1536 + c;
  #pragma unroll
  for (int k=0;k<3;k++)
    #pragma unroll
    for (int v=0;v<JJ;v++)
      y[k][v] = bf2f(gp[(size_t)v*1536 + k*512]);
  u16* xo = xg + (size_t)b*JJ*CC + c;
  for (int w=0;w<JJ;w++){
    float a=0.f;
    #pragma unroll
    for (int k=0;k<3;k++)
      #pragma unroll
      for (int v=0;v<JJ;v++)
        a += y[k][v]*adj_l[(k*17+v)*17+w];
    xo[(size_t)w*CC] = f2bf(a);
  }
}

// ---------------- attention over joints: one wave per head ----------------
__global__ __launch_bounds__(512) void k_attn(const u16* __restrict__ Gqkv, u16* __restrict__ sga){
  __shared__ u16 qs[8][JJ][64];
  __shared__ u16 ks_[8][JJ][64];
  __shared__ float at[8][JJ][JJ];
  int b = blockIdx.x, tid = threadIdx.x;
  int h = tid>>6, d = tid&63;
  const u16* base = Gqkv + (size_t)b*JJ*1536;
  float vv[JJ];
  #pragma unroll
  for (int i=0;i<JJ;i++){
    qs[h][i][d]  = base[(size_t)i*1536 +        h*64 + d];
    ks_[h][i][d] = base[(size_t)i*1536 +  512 + h*64 + d];
    vv[i] = bf2f(base[(size_t)i*1536 + 1024 + h*64 + d]);
  }
  __syncthreads();
  for (int p=d; p<289; p+=64){
    int i=p/17, j=p%17;
    float a=0.f;
    #pragma unroll
    for (int dd=0;dd<64;dd++) a += bf2f(qs[h][i][dd])*bf2f(ks_[h][j][dd]);
    at[h][i][j] = a*0.125f;   // 1/sqrt(64)
  }
  __syncthreads();
  if (d < JJ){
    float mx=-1e30f;
    #pragma unroll
    for (int j=0;j<JJ;j++) mx = fmaxf(mx, at[h][d][j]);
    float sm=0.f;
    #pragma unroll
    for (int j=0;j<JJ;j++){ float e=expf(at[h][d][j]-mx); at[h][d][j]=e; sm+=e; }
    float inv=1.f/sm;
    #pragma unroll
    for (int j=0;j<JJ;j++) at[h][d][j]*=inv;
  }
  __syncthreads();
  #pragma unroll
  for (int i=0;i<JJ;i++){
    float a=0.f;
    #pragma unroll
    for (int j=0;j<JJ;j++) a += at[h][i][j]*vv[j];
    sga[((size_t)b*JJ+i)*CC + h*64 + d] = f2bf(a);
  }
}

// ---------------- token MLP: J -> TOK(gelu) -> J ----------------
__global__ __launch_bounds__(512) void k_tok(const u16* __restrict__ Hpw,
    const float* __restrict__ w1, const float* __restrict__ b1,
    const float* __restrict__ w2, const float* __restrict__ b2,
    u16* __restrict__ h2o){
  __shared__ float w1s[64*17], w2s[17*64], b1s[64], b2s[17];
  int b = blockIdx.x, c = threadIdx.x;
  for (int i=c;i<1088;i+=512){ w1s[i]=w1[i]; w2s[i]=w2[i]; }
  if (c<64) b1s[c]=b1[c];
  if (c<17) b2s[c]=b2[c];
  __syncthreads();
  float hv[JJ];
  const u16* hp = Hpw + (size_t)b*JJ*CC + c;
  #pragma unroll
  for (int j=0;j<JJ;j++) hv[j]=bf2f(hp[(size_t)j*CC]);
  float a2[JJ];
  #pragma unroll
  for (int j=0;j<JJ;j++) a2[j]=b2s[j];
  for (int t=0;t<64;t++){
    float a=b1s[t];
    #pragma unroll
    for (int j=0;j<JJ;j++) a += hv[j]*w1s[t*17+j];
    a = gelu_f(a);
    #pragma unroll
    for (int j=0;j<JJ;j++) a2[j] += a*w2s[j*64+t];
  }
  u16* ho = h2o + (size_t)b*JJ*CC + c;
  #pragma unroll
  for (int j=0;j<JJ;j++) ho[(size_t)j*CC]=f2bf(a2[j]);
}

// ---------------- fuse: GN(gnf)+gelu -> rc ; LN(over C)(rc + x) -> xn ----------------
__global__ __launch_bounds__(512) void k_fuse(const u16* __restrict__ s,
    const float* __restrict__ x, int b0,
    const float* __restrict__ gfw, const float* __restrict__ gfb,
    const float* __restrict__ n2w, const float* __restrict__ n2b,
    u16* __restrict__ rc, u16* __restrict__ xn){
  __shared__ float rS[8][JJ], rQ[8][JJ];
  int b = blockIdx.x, c = threadIdx.x;
  int wave = c>>6, lane = c&63;
  const u16* sp = s + (size_t)b*JJ*CC + c;
  float sv[JJ];
  #pragma unroll
  for (int j=0;j<JJ;j++) sv[j]=bf2f(sp[(size_t)j*CC]);
  float ss=0.f, sq=0.f;
  #pragma unroll
  for (int j=0;j<JJ;j++){ ss+=sv[j]; sq+=sv[j]*sv[j]; }
  for (int off=32; off; off>>=1){ ss += __shfl_xor(ss,off); sq += __shfl_xor(sq,off); }
  float gm = ss*(1.f/1088.f);
  float gr = rsqrtf(sq*(1.f/1088.f) - gm*gm + 1e-5f);
  float gw=gfw[c], gb=gfb[c];
  const float* xp = x + (size_t)(b0+b)*JJ*CC + c;
  u16* rp = rc + (size_t)b*JJ*CC + c;
  float t[JJ];
  #pragma unroll
  for (int j=0;j<JJ;j++){
    float v = gelu_f((sv[j]-gm)*gr*gw + gb);
    rp[(size_t)j*CC] = f2bf(v);
    t[j] = v + xp[(size_t)j*CC];
  }
  #pragma unroll
  for (int j=0;j<JJ;j++){
    float a=t[j], q=a*a;
    for (int off=32; off; off>>=1){ a+=__shfl_xor(a,off); q+=__shfl_xor(q,off); }
    if (lane==0){ rS[wave][j]=a; rQ[wave][j]=q; }
  }
  __syncthreads();
  float wN=n2w[c], bN=n2b[c];
  u16* xo = xn + (size_t)b*JJ*CC + c;
  #pragma unroll
  for (int j=0;j<JJ;j++){
    float S=0.f,Q=0.f;
    #pragma unroll
    for (int w=0;w<8;w++){ S+=rS[w][j]; Q+=rQ[w][j]; }
    float mn=S*(1.f/512.f);
    float r2=rsqrtf(Q*(1.f/512.f)-mn*mn+1e-5f);
    xo[(size_t)j*CC]=f2bf((t[j]-mn)*r2*wN+bN);
  }
}

// ---------------- final: adj contract on G2 + residual sums, f32 out ----------------
__global__ __launch_bounds__(512) void k_final(const u16* __restrict__ G2, const u16* __restrict__ rc,
    const float* __restrict__ x, int b0,
    const float* __restrict__ adj, float* __restrict__ out){
  __shared__ float adj_l[867];
  int b = blockIdx.x, c = threadIdx.x;
  for (int i=c;i<867;i+=512) adj_l[i]=adj[i];
  __syncthreads();
  float y[3][JJ];
  const u16* gp = G2 + (size_t)b*JJ*1536 + c;
  #pragma unroll
  for (int k=0;k<3;k++)
    #pragma unroll
    for (int v=0;v<JJ;v++)
      y[k][v] = bf2f(gp[(size_t)v*1536 + k*512]);
  const size_t lbase = (size_t)b*JJ*CC + c;
  const size_t gbase = (size_t)(b0+b)*JJ*CC + c;
  for (int w=0;w<JJ;w++){
    float a=0.f;
    #pragma unroll
    for (int k=0;k<3;k++)
      #pragma unroll
      for (int v=0;v<JJ;v++)
        a += y[k][v]*adj_l[(k*17+v)*17+w];
    out[gbase + (size_t)w*CC] = a + bf2f(rc[lbase + (size_t)w*CC]) + x[gbase + (size_t)w*CC];
  }
}

extern "C" void kernel_launch(void* const* d_in, const int* in_sizes, int n_in,
                              void* d_out, int out_size, void* d_ws, size_t ws_size,
                              hipStream_t stream)
{
  const float* x      = (const float*)d_in[0];
  const float* adj    = (const float*)d_in[1];
  const float* n1w    = (const float*)d_in[2];
  const float* n1b    = (const float*)d_in[3];
  const float* gcn1_w = (const float*)d_in[4];
  const float* gcn1_b = (const float*)d_in[5];
  const float* dw_w   = (const float*)d_in[6];
  const float* dw_b   = (const float*)d_in[7];
  const float* gn1_w  = (const float*)d_in[8];
  const float* gn1_b  = (const float*)d_in[9];
  const float* pw_w   = (const float*)d_in[10];
  const float* pw_b   = (const float*)d_in[11];
  const float* m1w1   = (const float*)d_in[12];
  const float* m1b1   = (const float*)d_in[13];
  const float* m1w2   = (const float*)d_in[14];
  const float* m1b2   = (const float*)d_in[15];
  const float* qkv_w  = (const float*)d_in[16];
  const float* qkv_b  = (const float*)d_in[17];
  const float* proj_w = (const float*)d_in[18];
  const float* proj_b = (const float*)d_in[19];
  const float* gnf_w  = (const float*)d_in[20];
  const float* gnf_b  = (const float*)d_in[21];
  const float* n2w    = (const float*)d_in[22];
  const float* n2b    = (const float*)d_in[23];
  const float* m2w1   = (const float*)d_in[24];
  const float* m2b1   = (const float*)d_in[25];
  const float* m2w2   = (const float*)d_in[26];
  const float* m2b2   = (const float*)d_in[27];
  const float* gcn2_w = (const float*)d_in[28];
  const float* gcn2_b = (const float*)d_in[29];
  float* out = (float*)d_out;

  char* ws = (char*)d_ws;
  const size_t WBYTES = (size_t)3932160*2;   // bf16 weights: 7.86 MB

  // pick the largest batch-chunk that fits ws_size (deterministic: ws_size is fixed)
  const int cands[6] = {4096,2048,1024,512,256,128};
  int NB = 0;
  for (int ci=0; ci<6; ci++){
    size_t need = WBYTES + (size_t)cands[ci]*JJ*2*(1536 + 4*512);
    if (need <= ws_size){ NB = cands[ci]; break; }
  }
  if (NB == 0) return;   // < 24 MB of scratch: cannot run

  u16* wb = (u16*)ws;
  char* p = ws + WBYTES;
  const size_t SZ_BIGc = (size_t)NB*JJ*1536*2;
  const size_t SZTc    = (size_t)NB*JJ*512*2;
  u16* big = (u16*)p;               p += SZ_BIGc;
  u16* t0  = (u16*)p;               p += SZTc;   // xc -> Hpw -> s -> m2
  u16* t1  = (u16*)p;               p += SZTc;   // hgn -> h2 -> rc
  u16* t2  = (u16*)p;               p += SZTc;   // xg -> xn
  u16* t3  = (u16*)p;                            // sga

  u16 *wg1=wb, *wqkv=wb+786432, *wpw=wb+1572864, *wproj=wb+1835008,
      *wm1=wb+2097152, *wm2=wb+2621440, *wg2=wb+3145728;

  // weight converts (f32 -> bf16), once
  k_cvt<<<(786432+255)/256,256,0,stream>>>(gcn1_w,wg1,786432);
  k_cvt<<<(786432+255)/256,256,0,stream>>>(qkv_w,wqkv,786432);
  k_cvt<<<(262144+255)/256,256,0,stream>>>(pw_w,wpw,262144);
  k_cvt<<<(262144+255)/256,256,0,stream>>>(proj_w,wproj,262144);
  k_cvt<<<(524288+255)/256,256,0,stream>>>(m2w1,wm1,524288);
  k_cvt<<<(524288+255)/256,256,0,stream>>>(m2w2,wm2,524288);
  k_cvt<<<(786432+255)/256,256,0,stream>>>(gcn2_w,wg2,786432);

  const int M2 = NB*JJ;           // tokens per chunk (multiple of 128 since 128 | NB)
  const dim3 blk(256);
  for (int b0 = 0; b0 < BB; b0 += NB){
    k_pre<<<NB,512,0,stream>>>(x,b0,n1w,n1b,dw_w,dw_b,gn1_w,gn1_b, t0/*xc*/, t1/*hgn*/);
    // GCN1
    gemm_bt<0,0><<<dim3(12,M2/128),blk,0,stream>>>(t0,wg1,gcn1_b,big,nullptr,nullptr,M2,1536,512);
    k_gcn<<<NB,512,0,stream>>>(big,adj,t2/*xg*/);
    // QKV + attention
    gemm_bt<0,0><<<dim3(12,M2/128),blk,0,stream>>>(t0,wqkv,qkv_b,big,nullptr,nullptr,M2,1536,512);
    k_attn<<<NB,512,0,stream>>>(big,t3/*sga*/);
    // pw + token MLP  (xc dead -> t0 reused for Hpw)
    gemm_bt<0,0><<<dim3(4,M2/128),blk,0,stream>>>(t1,wpw,pw_b,t0/*Hpw*/,nullptr,nullptr,M2,512,512);
    k_tok<<<NB,512,0,stream>>>(t0,m1w1,m1b1,m1w2,m1b2,t1/*h2*/);
    // proj + branch merge: s = proj(sga)+b + xg + h2
    gemm_bt<0,1><<<dim3(4,M2/128),blk,0,stream>>>(t3,wproj,proj_b,t0/*s*/,t2,t1,M2,512,512);
    // GN(gnf)+gelu -> rc ; LN2(rc+x) -> xn
    k_fuse<<<NB,512,0,stream>>>(t0,x,b0,gnf_w,gnf_b,n2w,n2b,t1/*rc*/,t2/*xn*/);
    // MLP2
    gemm_bt<1,0><<<dim3(8,M2/128),blk,0,stream>>>(t2,wm1,m2b1,big/*m*/,nullptr,nullptr,M2,1024,512);
    gemm_bt<0,0><<<dim3(4,M2/128),blk,0,stream>>>(big,wm2,m2b2,t0/*m2*/,nullptr,nullptr,M2,512,1024);
    // GCN2
    gemm_bt<0,0><<<dim3(12,M2/128),blk,0,stream>>>(t0,wg2,gcn2_b,big/*G2*/,nullptr,nullptr,M2,1536,512);
    k_final<<<NB,512,0,stream>>>(big,t1/*rc*/,x,b0,adj,out);
  }
}

// Round 3
// 1626.930 us; speedup vs baseline: 1.3327x; 1.3327x over previous
//
#include <hip/hip_runtime.h>
#include <stdint.h>

#define BB 4096
#define JJ 17
#define CC 512

typedef unsigned short u16;
typedef __bf16 bf16x8 __attribute__((ext_vector_type(8)));
typedef float  f32x4  __attribute__((ext_vector_type(4)));

__device__ __forceinline__ float bf2f(u16 u){ return __uint_as_float(((uint32_t)u)<<16); }
__device__ __forceinline__ u16 f2bf(float f){
  uint32_t u = __float_as_uint(f);
  u += 0x7fffu + ((u>>16)&1u);           // round-to-nearest-even
  return (u16)(u>>16);
}
__device__ __forceinline__ void unpk2(uint32_t u, float& lo, float& hi){
  lo = __uint_as_float(u<<16);
  hi = __uint_as_float(u & 0xffff0000u);
}
__device__ __forceinline__ float gelu_f(float x){
  return 0.5f*x*(1.f+erff(x*0.70710678118654752f));
}
__device__ __forceinline__ void gll16(const void* g, void* l){
  __builtin_amdgcn_global_load_lds(
      (const __attribute__((address_space(1))) void*)g,
      (__attribute__((address_space(3))) void*)l, 16, 0, 0);
}

// ---------------- weight f32 -> bf16 convert ----------------
__global__ void k_cvt(const float* __restrict__ in, u16* __restrict__ out, int n){
  int i = blockIdx.x*blockDim.x + threadIdx.x;
  if (i < n) out[i] = f2bf(in[i]);
}

// ---------------- token-MLP weight prep: pad rows to 20, transpose w2 ----------------
__global__ void k_tokprep(const float* __restrict__ w1, const float* __restrict__ w2,
                          float* __restrict__ w1p, float* __restrict__ w2p){
  int i = blockIdx.x*blockDim.x + threadIdx.x;     // 0..1279
  if (i >= 1280) return;
  int t = i/20, j = i%20;
  w1p[i] = (j<17) ? w1[t*17+j] : 0.f;
  w2p[i] = (j<17) ? w2[j*64+t] : 0.f;
}

// ---------------- pre: LN(over J) + dwconv + GN1 + gelu ----------------
__global__ __launch_bounds__(512) void k_pre(
    const float* __restrict__ x, int b0,
    const float* __restrict__ n1w, const float* __restrict__ n1b,
    const float* __restrict__ dww, const float* __restrict__ dwb,
    const float* __restrict__ gn1w, const float* __restrict__ gn1b,
    u16* __restrict__ xc, u16* __restrict__ hgn)
{
  int b = blockIdx.x, c = threadIdx.x;
  const float* xp = x + (size_t)(b0+b)*JJ*CC + c;
  float v[JJ]; float s = 0.f;
  #pragma unroll
  for (int j=0;j<JJ;j++){ v[j] = xp[(size_t)j*CC]; s += v[j]; }
  float mn = s*(1.f/JJ); float var = 0.f;
  #pragma unroll
  for (int j=0;j<JJ;j++){ float d=v[j]-mn; var += d*d; }
  float rr = rsqrtf(var*(1.f/JJ)+1e-5f);
  float xcv[JJ];
  #pragma unroll
  for (int j=0;j<JJ;j++) xcv[j] = (v[j]-mn)*rr*n1w[j] + n1b[j];
  u16* xo = xc + (size_t)b*JJ*CC + c;
  #pragma unroll
  for (int j=0;j<JJ;j++) xo[(size_t)j*CC] = f2bf(xcv[j]);
  float w0=dww[c*3+0], w1=dww[c*3+1], w2=dww[c*3+2], db=dwb[c];
  float h[JJ];
  #pragma unroll
  for (int j=0;j<JJ;j++){
    float a = db + w1*xcv[j];
    if (j>0)    a += w0*xcv[j-1];
    if (j<JJ-1) a += w2*xcv[j+1];
    h[j] = a;
  }
  float ss=0.f, sq=0.f;
  #pragma unroll
  for (int j=0;j<JJ;j++){ ss += h[j]; sq += h[j]*h[j]; }
  for (int off=32; off; off>>=1){ ss += __shfl_xor(ss,off); sq += __shfl_xor(sq,off); }
  float gm = ss*(1.f/(64.f*JJ));
  float gr = rsqrtf(sq*(1.f/(64.f*JJ)) - gm*gm + 1e-5f);
  float gw = gn1w[c], gb = gn1b[c];
  u16* ho = hgn + (size_t)b*JJ*CC + c;
  #pragma unroll
  for (int j=0;j<JJ;j++){
    float t = (h[j]-gm)*gr*gw + gb;
    ho[(size_t)j*CC] = f2bf(gelu_f(t));
  }
}

// ---------------- MFMA GEMM: out[M,N] = A[M,K] @ W[N,K]^T (+bias)(+adds)(+gelu) ----------------
template<int DO_GELU, int DO_ADD>
__global__ __launch_bounds__(256) void gemm_bt(
    const u16* __restrict__ A, const u16* __restrict__ W, const float* __restrict__ bias,
    u16* __restrict__ out, const u16* __restrict__ add0, const u16* __restrict__ add1,
    int M, int N, int K)
{
  __shared__ __align__(16) u16 As[128*32];
  __shared__ __align__(16) u16 Bs[128*32];
  const int tid = threadIdx.x;
  const int wave = tid>>6, lane = tid&63;
  const int m0 = blockIdx.y*128, n0 = blockIdx.x*128;
  const int wm = (wave>>1)*64, wn = (wave&1)*64;
  f32x4 acc[4][4];
  const f32x4 z = {0.f,0.f,0.f,0.f};
  #pragma unroll
  for (int i=0;i<4;i++)
    #pragma unroll
    for (int j=0;j<4;j++) acc[i][j]=z;

  const u16* gA = A + (size_t)(m0 + (tid>>2))*K + (tid&3)*8;
  const u16* gB = W + (size_t)(n0 + (tid>>2))*K + (tid&3)*8;
  u16* lA = As + wave*512;
  u16* lB = Bs + wave*512;
  const size_t r64 = (size_t)64*K;
  const int lr = lane&15, kg = (lane>>4)*8;

  for (int kk=0; kk<K; kk+=32){
    gll16(gA+kk,      lA);
    gll16(gA+kk+r64,  lA+2048);
    gll16(gB+kk,      lB);
    gll16(gB+kk+r64,  lB+2048);
    asm volatile("s_waitcnt vmcnt(0)" ::: "memory");
    __syncthreads();
    bf16x8 av[4], bv[4];
    #pragma unroll
    for (int i=0;i<4;i++) av[i] = *(const bf16x8*)&As[(wm+i*16+lr)*32 + kg];
    #pragma unroll
    for (int j=0;j<4;j++) bv[j] = *(const bf16x8*)&Bs[(wn+j*16+lr)*32 + kg];
    #pragma unroll
    for (int i=0;i<4;i++)
      #pragma unroll
      for (int j=0;j<4;j++)
        acc[i][j] = __builtin_amdgcn_mfma_f32_16x16x32_bf16(av[i], bv[j], acc[i][j], 0,0,0);
    __syncthreads();
  }

  const int rbase = (lane>>4)*4;
  #pragma unroll
  for (int i=0;i<4;i++){
    #pragma unroll
    for (int j=0;j<4;j++){
      const int col  = n0 + wn + j*16 + lr;
      const int row0 = m0 + wm + i*16 + rbase;
      const float bvl = bias[col];
      #pragma unroll
      for (int r=0;r<4;r++){
        size_t idx = (size_t)(row0+r)*N + col;
        float v = acc[i][j][r] + bvl;
        if (DO_ADD)  v += bf2f(add0[idx]) + bf2f(add1[idx]);
        if (DO_GELU) v = gelu_f(v);
        out[idx] = f2bf(v);
      }
    }
  }
}

// ---------------- adj contraction (and final variant): vectorized ----------------
// FINAL=0: xg[(bl,w),c] = sum_{k,v} G[(bl,v),k*512+c]*adj[k,v,w]   (bf16 out)
// FINAL=1: out_f32 = contraction + rc + x  (global residual sum)
template<int FINAL>
__global__ __launch_bounds__(512) void k_gcn2(
    const u16* __restrict__ G, const float* __restrict__ adj,
    u16* __restrict__ xg,
    const u16* __restrict__ rc, const float* __restrict__ x, int b0,
    float* __restrict__ out)
{
  __shared__ __align__(16) float adjp[51*20];     // rows padded to 20 f32 (80B, 16B-aligned)
  const int tid = threadIdx.x;
  for (int i=tid; i<1020; i+=512){
    int r=i/20, cl=i%20;
    adjp[i] = (cl<17) ? adj[r*17+cl] : 0.f;
  }
  __syncthreads();

  const int sl  = tid>>7;            // sample within block (0..3)
  const int l   = tid&127;           // lane within sample
  const int c0  = l*4;               // 4 channels per thread
  const int bl  = blockIdx.x*4 + sl; // chunk-local sample

  float acc[JJ][4];
  #pragma unroll
  for (int w=0;w<JJ;w++)
    #pragma unroll
    for (int e=0;e<4;e++) acc[w][e]=0.f;

  const u16* gbase = G + (size_t)bl*JJ*1536 + c0;
  #pragma unroll 3
  for (int kv=0; kv<51; kv++){
    const int k = kv/JJ, v = kv - k*JJ;
    uint2 yu = *(const uint2*)(gbase + (size_t)v*1536 + k*512);
    float y0,y1,y2,y3;
    unpk2(yu.x, y0, y1);
    unpk2(yu.y, y2, y3);
    const f32x4* arow = (const f32x4*)&adjp[kv*20];
    f32x4 a0=arow[0], a1=arow[1], a2=arow[2], a3=arow[3];
    float a16 = adjp[kv*20+16];
    float ar[JJ] = {a0[0],a0[1],a0[2],a0[3], a1[0],a1[1],a1[2],a1[3],
                    a2[0],a2[1],a2[2],a2[3], a3[0],a3[1],a3[2],a3[3], a16};
    #pragma unroll
    for (int w=0;w<JJ;w++){
      acc[w][0] += y0*ar[w];
      acc[w][1] += y1*ar[w];
      acc[w][2] += y2*ar[w];
      acc[w][3] += y3*ar[w];
    }
  }

  if (FINAL==0){
    u16* xo = xg + (size_t)bl*JJ*CC + c0;
    #pragma unroll
    for (int w=0;w<JJ;w++){
      uint2 o;
      o.x = (uint32_t)f2bf(acc[w][0]) | ((uint32_t)f2bf(acc[w][1])<<16);
      o.y = (uint32_t)f2bf(acc[w][2]) | ((uint32_t)f2bf(acc[w][3])<<16);
      *(uint2*)(xo + (size_t)w*CC) = o;
    }
  } else {
    const size_t gb = (size_t)(b0+bl)*JJ*CC + c0;
    const u16* rp = rc + (size_t)bl*JJ*CC + c0;
    #pragma unroll
    for (int w=0;w<JJ;w++){
      uint2 ru = *(const uint2*)(rp + (size_t)w*CC);
      float r0,r1,r2,r3;
      unpk2(ru.x, r0, r1);
      unpk2(ru.y, r2, r3);
      f32x4 xv = *(const f32x4*)(x + gb + (size_t)w*CC);
      f32x4 o;
      o[0]=acc[w][0]+r0+xv[0]; o[1]=acc[w][1]+r1+xv[1];
      o[2]=acc[w][2]+r2+xv[2]; o[3]=acc[w][3]+r3+xv[3];
      *(f32x4*)(out + gb + (size_t)w*CC) = o;
    }
  }
}

// ---------------- attention over joints: one wave per head, vectorized ----------------
__global__ __launch_bounds__(512) void k_attn(const u16* __restrict__ Gqkv, u16* __restrict__ sga){
  __shared__ __align__(16) u16 qs[8*17*72];     // rows padded 64->72 (144B)
  __shared__ __align__(16) u16 ks_[8*17*72];
  __shared__ __align__(16) float at[8*17*20];   // rows padded 17->20 (80B)
  int b = blockIdx.x, tid = threadIdx.x;
  int h = tid>>6, d = tid&63;
  const u16* base = Gqkv + (size_t)b*JJ*1536;
  float vv[JJ];
  #pragma unroll
  for (int i=0;i<JJ;i++){
    qs [(h*JJ+i)*72 + d] = base[(size_t)i*1536 +        h*64 + d];
    ks_[(h*JJ+i)*72 + d] = base[(size_t)i*1536 +  512 + h*64 + d];
    vv[i] = bf2f(base[(size_t)i*1536 + 1024 + h*64 + d]);
  }
  __syncthreads();
  for (int p=d; p<289; p+=64){
    int i=p/JJ, j=p-i*JJ;
    const u16* qrow = &qs [(h*JJ+i)*72];
    const u16* krow = &ks_[(h*JJ+j)*72];
    float a=0.f;
    #pragma unroll
    for (int t=0;t<8;t++){
      bf16x8 q8 = *(const bf16x8*)&qrow[t*8];
      bf16x8 k8 = *(const bf16x8*)&krow[t*8];
      #pragma unroll
      for (int e=0;e<8;e++) a += (float)q8[e]*(float)k8[e];
    }
    at[(h*JJ+i)*20 + j] = a*0.125f;
  }
  __syncthreads();
  if (d < JJ){
    float* row = &at[(h*JJ+d)*20];
    f32x4 r0=((f32x4*)row)[0], r1=((f32x4*)row)[1], r2=((f32x4*)row)[2], r3=((f32x4*)row)[3];
    float e16=row[16];
    float rv[JJ]={r0[0],r0[1],r0[2],r0[3],r1[0],r1[1],r1[2],r1[3],
                  r2[0],r2[1],r2[2],r2[3],r3[0],r3[1],r3[2],r3[3],e16};
    float mx=-1e30f;
    #pragma unroll
    for (int j=0;j<JJ;j++) mx=fmaxf(mx,rv[j]);
    float sm=0.f;
    #pragma unroll
    for (int j=0;j<JJ;j++){ rv[j]=expf(rv[j]-mx); sm+=rv[j]; }
    float inv=1.f/sm;
    #pragma unroll
    for (int j=0;j<JJ;j++) row[j]=rv[j]*inv;
  }
  __syncthreads();
  #pragma unroll
  for (int i=0;i<JJ;i++){
    const float* row = &at[(h*JJ+i)*20];
    f32x4 r0=((const f32x4*)row)[0], r1=((const f32x4*)row)[1],
          r2=((const f32x4*)row)[2], r3=((const f32x4*)row)[3];
    float a = r0[0]*vv[0]+r0[1]*vv[1]+r0[2]*vv[2]+r0[3]*vv[3]
            + r1[0]*vv[4]+r1[1]*vv[5]+r1[2]*vv[6]+r1[3]*vv[7]
            + r2[0]*vv[8]+r2[1]*vv[9]+r2[2]*vv[10]+r2[3]*vv[11]
            + r3[0]*vv[12]+r3[1]*vv[13]+r3[2]*vv[14]+r3[3]*vv[15]
            + row[16]*vv[16];
    sga[((size_t)b*JJ+i)*CC + h*64 + d] = f2bf(a);
  }
}

// ---------------- token MLP: J -> TOK(gelu) -> J (padded weights, 2 ch/thread) ----------------
__global__ __launch_bounds__(512) void k_tok(const u16* __restrict__ Hpw,
    const float* __restrict__ w1p, const float* __restrict__ w2p,
    const float* __restrict__ b1, const float* __restrict__ b2,
    u16* __restrict__ h2o){
  __shared__ __align__(16) float w1s[1280], w2s[1280];
  __shared__ float b1s[64], b2s[JJ];
  const int tid = threadIdx.x;
  for (int i=tid; i<1280; i+=512){ w1s[i]=w1p[i]; w2s[i]=w2p[i]; }
  if (tid<64) b1s[tid]=b1[tid];
  if (tid<JJ) b2s[tid]=b2[tid];
  __syncthreads();

  const int bl = blockIdx.x*2 + (tid>>8);   // sample
  const int c0 = tid&255;                   // channels c0, c0+256
  const u16* hp = Hpw + (size_t)bl*JJ*CC;
  float hv0[JJ], hv1[JJ];
  #pragma unroll
  for (int j=0;j<JJ;j++){
    hv0[j]=bf2f(hp[(size_t)j*CC + c0]);
    hv1[j]=bf2f(hp[(size_t)j*CC + c0 + 256]);
  }
  float a20[JJ], a21[JJ];
  #pragma unroll
  for (int j=0;j<JJ;j++){ a20[j]=b2s[j]; a21[j]=b2s[j]; }

  for (int t=0;t<64;t++){
    float wr[20];
    *(f32x4*)&wr[0]  = *(const f32x4*)&w1s[t*20];
    *(f32x4*)&wr[4]  = *(const f32x4*)&w1s[t*20+4];
    *(f32x4*)&wr[8]  = *(const f32x4*)&w1s[t*20+8];
    *(f32x4*)&wr[12] = *(const f32x4*)&w1s[t*20+12];
    wr[16] = w1s[t*20+16];
    float a0=b1s[t], a1=b1s[t];
    #pragma unroll
    for (int j=0;j<JJ;j++){ a0 += hv0[j]*wr[j]; a1 += hv1[j]*wr[j]; }
    a0 = gelu_f(a0); a1 = gelu_f(a1);
    *(f32x4*)&wr[0]  = *(const f32x4*)&w2s[t*20];
    *(f32x4*)&wr[4]  = *(const f32x4*)&w2s[t*20+4];
    *(f32x4*)&wr[8]  = *(const f32x4*)&w2s[t*20+8];
    *(f32x4*)&wr[12] = *(const f32x4*)&w2s[t*20+12];
    wr[16] = w2s[t*20+16];
    #pragma unroll
    for (int j=0;j<JJ;j++){ a20[j] += a0*wr[j]; a21[j] += a1*wr[j]; }
  }
  u16* ho = h2o + (size_t)bl*JJ*CC;
  #pragma unroll
  for (int j=0;j<JJ;j++){
    ho[(size_t)j*CC + c0]       = f2bf(a20[j]);
    ho[(size_t)j*CC + c0 + 256] = f2bf(a21[j]);
  }
}

// ---------------- fuse: GN(gnf)+gelu -> rc ; LN(over C)(rc + x) -> xn ----------------
__global__ __launch_bounds__(512) void k_fuse(const u16* __restrict__ s,
    const float* __restrict__ x, int b0,
    const float* __restrict__ gfw, const float* __restrict__ gfb,
    const float* __restrict__ n2w, const float* __restrict__ n2b,
    u16* __restrict__ rc, u16* __restrict__ xn){
  __shared__ float rS[8][JJ], rQ[8][JJ];
  int b = blockIdx.x, c = threadIdx.x;
  int wave = c>>6, lane = c&63;
  const u16* sp = s + (size_t)b*JJ*CC + c;
  float sv[JJ];
  #pragma unroll
  for (int j=0;j<JJ;j++) sv[j]=bf2f(sp[(size_t)j*CC]);
  float ss=0.f, sq=0.f;
  #pragma unroll
  for (int j=0;j<JJ;j++){ ss+=sv[j]; sq+=sv[j]*sv[j]; }
  for (int off=32; off; off>>=1){ ss += __shfl_xor(ss,off); sq += __shfl_xor(sq,off); }
  float gm = ss*(1.f/1088.f);
  float gr = rsqrtf(sq*(1.f/1088.f) - gm*gm + 1e-5f);
  float gw=gfw[c], gb=gfb[c];
  const float* xp = x + (size_t)(b0+b)*JJ*CC + c;
  u16* rp = rc + (size_t)b*JJ*CC + c;
  float t[JJ];
  #pragma unroll
  for (int j=0;j<JJ;j++){
    float v = gelu_f((sv[j]-gm)*gr*gw + gb);
    rp[(size_t)j*CC] = f2bf(v);
    t[j] = v + xp[(size_t)j*CC];
  }
  #pragma unroll
  for (int j=0;j<JJ;j++){
    float a=t[j], q=a*a;
    for (int off=32; off; off>>=1){ a+=__shfl_xor(a,off); q+=__shfl_xor(q,off); }
    if (lane==0){ rS[wave][j]=a; rQ[wave][j]=q; }
  }
  __syncthreads();
  float wN=n2w[c], bN=n2b[c];
  u16* xo = xn + (size_t)b*JJ*CC + c;
  #pragma unroll
  for (int j=0;j<JJ;j++){
    float S=0.f,Q=0.f;
    #pragma unroll
    for (int w=0;w<8;w++){ S+=rS[w][j]; Q+=rQ[w][j]; }
    float mn=S*(1.f/512.f);
    float r2=rsqrtf(Q*(1.f/512.f)-mn*mn+1e-5f);
    xo[(size_t)j*CC]=f2bf((t[j]-mn)*r2*wN+bN);
  }
}

extern "C" void kernel_launch(void* const* d_in, const int* in_sizes, int n_in,
                              void* d_out, int out_size, void* d_ws, size_t ws_size,
                              hipStream_t stream)
{
  const float* x      = (const float*)d_in[0];
  const float* adj    = (const float*)d_in[1];
  const float* n1w    = (const float*)d_in[2];
  const float* n1b    = (const float*)d_in[3];
  const float* gcn1_w = (const float*)d_in[4];
  const float* gcn1_b = (const float*)d_in[5];
  const float* dw_w   = (const float*)d_in[6];
  const float* dw_b   = (const float*)d_in[7];
  const float* gn1_w  = (const float*)d_in[8];
  const float* gn1_b  = (const float*)d_in[9];
  const float* pw_w   = (const float*)d_in[10];
  const float* pw_b   = (const float*)d_in[11];
  const float* m1w1   = (const float*)d_in[12];
  const float* m1b1   = (const float*)d_in[13];
  const float* m1w2   = (const float*)d_in[14];
  const float* m1b2   = (const float*)d_in[15];
  const float* qkv_w  = (const float*)d_in[16];
  const float* qkv_b  = (const float*)d_in[17];
  const float* proj_w = (const float*)d_in[18];
  const float* proj_b = (const float*)d_in[19];
  const float* gnf_w  = (const float*)d_in[20];
  const float* gnf_b  = (const float*)d_in[21];
  const float* n2w    = (const float*)d_in[22];
  const float* n2b    = (const float*)d_in[23];
  const float* m2w1   = (const float*)d_in[24];
  const float* m2b1   = (const float*)d_in[25];
  const float* m2w2   = (const float*)d_in[26];
  const float* m2b2   = (const float*)d_in[27];
  const float* gcn2_w = (const float*)d_in[28];
  const float* gcn2_b = (const float*)d_in[29];
  float* out = (float*)d_out;

  char* ws = (char*)d_ws;
  const size_t WBYTES = (size_t)3932160*2;   // bf16 weights: 7.86 MB
  const size_t TPBYTES = 2560*4;             // padded token-MLP weights (f32)

  const int cands[6] = {4096,2048,1024,512,256,128};
  int NB = 0;
  for (int ci=0; ci<6; ci++){
    size_t need = WBYTES + TPBYTES + (size_t)cands[ci]*JJ*2*(1536 + 4*512);
    if (need <= ws_size){ NB = cands[ci]; break; }
  }
  if (NB == 0) return;

  u16* wb = (u16*)ws;
  float* w1p = (float*)(ws + WBYTES);
  float* w2p = w1p + 1280;
  char* p = ws + WBYTES + TPBYTES;
  const size_t SZ_BIGc = (size_t)NB*JJ*1536*2;
  const size_t SZTc    = (size_t)NB*JJ*512*2;
  u16* big = (u16*)p;               p += SZ_BIGc;
  u16* t0  = (u16*)p;               p += SZTc;   // xc -> Hpw -> s -> m2
  u16* t1  = (u16*)p;               p += SZTc;   // hgn -> h2 -> rc
  u16* t2  = (u16*)p;               p += SZTc;   // xg -> xn
  u16* t3  = (u16*)p;                            // sga

  u16 *wg1=wb, *wqkv=wb+786432, *wpw=wb+1572864, *wproj=wb+1835008,
      *wm1=wb+2097152, *wm2=wb+2621440, *wg2=wb+3145728;

  k_cvt<<<(786432+255)/256,256,0,stream>>>(gcn1_w,wg1,786432);
  k_cvt<<<(786432+255)/256,256,0,stream>>>(qkv_w,wqkv,786432);
  k_cvt<<<(262144+255)/256,256,0,stream>>>(pw_w,wpw,262144);
  k_cvt<<<(262144+255)/256,256,0,stream>>>(proj_w,wproj,262144);
  k_cvt<<<(524288+255)/256,256,0,stream>>>(m2w1,wm1,524288);
  k_cvt<<<(524288+255)/256,256,0,stream>>>(m2w2,wm2,524288);
  k_cvt<<<(786432+255)/256,256,0,stream>>>(gcn2_w,wg2,786432);
  k_tokprep<<<5,256,0,stream>>>(m1w1,m1w2,w1p,w2p);

  const int M2 = NB*JJ;
  const dim3 blk(256);
  for (int b0 = 0; b0 < BB; b0 += NB){
    k_pre<<<NB,512,0,stream>>>(x,b0,n1w,n1b,dw_w,dw_b,gn1_w,gn1_b, t0/*xc*/, t1/*hgn*/);
    // GCN1
    gemm_bt<0,0><<<dim3(12,M2/128),blk,0,stream>>>(t0,wg1,gcn1_b,big,nullptr,nullptr,M2,1536,512);
    k_gcn2<0><<<NB/4,512,0,stream>>>(big,adj,t2/*xg*/,nullptr,nullptr,0,nullptr);
    // QKV + attention
    gemm_bt<0,0><<<dim3(12,M2/128),blk,0,stream>>>(t0,wqkv,qkv_b,big,nullptr,nullptr,M2,1536,512);
    k_attn<<<NB,512,0,stream>>>(big,t3/*sga*/);
    // pw + token MLP  (xc dead -> t0 reused for Hpw)
    gemm_bt<0,0><<<dim3(4,M2/128),blk,0,stream>>>(t1,wpw,pw_b,t0/*Hpw*/,nullptr,nullptr,M2,512,512);
    k_tok<<<NB/2,512,0,stream>>>(t0,w1p,w2p,m1b1,m1b2,t1/*h2*/);
    // proj + branch merge: s = proj(sga)+b + xg + h2
    gemm_bt<0,1><<<dim3(4,M2/128),blk,0,stream>>>(t3,wproj,proj_b,t0/*s*/,t2,t1,M2,512,512);
    // GN(gnf)+gelu -> rc ; LN2(rc+x) -> xn
    k_fuse<<<NB,512,0,stream>>>(t0,x,b0,gnf_w,gnf_b,n2w,n2b,t1/*rc*/,t2/*xn*/);
    // MLP2
    gemm_bt<1,0><<<dim3(8,M2/128),blk,0,stream>>>(t2,wm1,m2b1,big/*m*/,nullptr,nullptr,M2,1024,512);
    gemm_bt<0,0><<<dim3(4,M2/128),blk,0,stream>>>(big,wm2,m2b2,t0/*m2*/,nullptr,nullptr,M2,512,1024);
    // GCN2
    gemm_bt<0,0><<<dim3(12,M2/128),blk,0,stream>>>(t0,wg2,gcn2_b,big/*G2*/,nullptr,nullptr,M2,1536,512);
    k_gcn2<1><<<NB/4,512,0,stream>>>(big,adj,nullptr,t1/*rc*/,x,b0,out);
  }
}

// Round 4
// 1518.389 us; speedup vs baseline: 1.4280x; 1.0715x over previous
//
#include <hip/hip_runtime.h>
#include <stdint.h>

#define BB 4096
#define JJ 17
#define CC 512

typedef unsigned short u16;
typedef __bf16 bf16x8 __attribute__((ext_vector_type(8)));
typedef float  f32x4  __attribute__((ext_vector_type(4)));

__device__ __forceinline__ float bf2f(u16 u){ return __uint_as_float(((uint32_t)u)<<16); }
__device__ __forceinline__ u16 f2bf(float f){
  uint32_t u = __float_as_uint(f);
  u += 0x7fffu + ((u>>16)&1u);           // round-to-nearest-even
  return (u16)(u>>16);
}
__device__ __forceinline__ void unpk2(uint32_t u, float& lo, float& hi){
  lo = __uint_as_float(u<<16);
  hi = __uint_as_float(u & 0xffff0000u);
}
__device__ __forceinline__ float gelu_f(float x){
  return 0.5f*x*(1.f+erff(x*0.70710678118654752f));
}
__device__ __forceinline__ void gll16(const void* g, void* l){
  __builtin_amdgcn_global_load_lds(
      (const __attribute__((address_space(1))) void*)g,
      (__attribute__((address_space(3))) void*)l, 16, 0, 0);
}

// ---------------- weight f32 -> bf16 convert ----------------
__global__ void k_cvt(const float* __restrict__ in, u16* __restrict__ out, int n){
  int i = blockIdx.x*blockDim.x + threadIdx.x;
  if (i < n) out[i] = f2bf(in[i]);
}

// ---------------- token-MLP weight prep: pad rows to 20, transpose w2 ----------------
__global__ void k_tokprep(const float* __restrict__ w1, const float* __restrict__ w2,
                          float* __restrict__ w1p, float* __restrict__ w2p){
  int i = blockIdx.x*blockDim.x + threadIdx.x;     // 0..1279
  if (i >= 1280) return;
  int t = i/20, j = i%20;
  w1p[i] = (j<17) ? w1[t*17+j] : 0.f;
  w2p[i] = (j<17) ? w2[j*64+t] : 0.f;
}

// ---------------- pre: LN(over J) + dwconv + GN1 + gelu ----------------
__global__ __launch_bounds__(512) void k_pre(
    const float* __restrict__ x, int b0,
    const float* __restrict__ n1w, const float* __restrict__ n1b,
    const float* __restrict__ dww, const float* __restrict__ dwb,
    const float* __restrict__ gn1w, const float* __restrict__ gn1b,
    u16* __restrict__ xc, u16* __restrict__ hgn)
{
  int b = blockIdx.x, c = threadIdx.x;
  const float* xp = x + (size_t)(b0+b)*JJ*CC + c;
  float v[JJ]; float s = 0.f;
  #pragma unroll
  for (int j=0;j<JJ;j++){ v[j] = xp[(size_t)j*CC]; s += v[j]; }
  float mn = s*(1.f/JJ); float var = 0.f;
  #pragma unroll
  for (int j=0;j<JJ;j++){ float d=v[j]-mn; var += d*d; }
  float rr = rsqrtf(var*(1.f/JJ)+1e-5f);
  float xcv[JJ];
  #pragma unroll
  for (int j=0;j<JJ;j++) xcv[j] = (v[j]-mn)*rr*n1w[j] + n1b[j];
  u16* xo = xc + (size_t)b*JJ*CC + c;
  #pragma unroll
  for (int j=0;j<JJ;j++) xo[(size_t)j*CC] = f2bf(xcv[j]);
  float w0=dww[c*3+0], w1=dww[c*3+1], w2=dww[c*3+2], db=dwb[c];
  float h[JJ];
  #pragma unroll
  for (int j=0;j<JJ;j++){
    float a = db + w1*xcv[j];
    if (j>0)    a += w0*xcv[j-1];
    if (j<JJ-1) a += w2*xcv[j+1];
    h[j] = a;
  }
  float ss=0.f, sq=0.f;
  #pragma unroll
  for (int j=0;j<JJ;j++){ ss += h[j]; sq += h[j]*h[j]; }
  for (int off=32; off; off>>=1){ ss += __shfl_xor(ss,off); sq += __shfl_xor(sq,off); }
  float gm = ss*(1.f/(64.f*JJ));
  float gr = rsqrtf(sq*(1.f/(64.f*JJ)) - gm*gm + 1e-5f);
  float gw = gn1w[c], gb = gn1b[c];
  u16* ho = hgn + (size_t)b*JJ*CC + c;
  #pragma unroll
  for (int j=0;j<JJ;j++){
    float t = (h[j]-gm)*gr*gw + gb;
    ho[(size_t)j*CC] = f2bf(gelu_f(t));
  }
}

// ---------------- 256x256x64 8-wave pipelined MFMA GEMM ----------------
// out[M,N] = A[M,K] @ W[N,K]^T (+bias)(+adds)(+gelu). M%256==0, N%256==0, K%64==0.
template<int DO_GELU, int DO_ADD>
__global__ __launch_bounds__(512,2) void gemm256(
    const u16* __restrict__ A, const u16* __restrict__ W, const float* __restrict__ bias,
    u16* __restrict__ out, const u16* __restrict__ add0, const u16* __restrict__ add1,
    int M, int N, int K, int NXT)
{
  __shared__ __align__(16) u16 lds[65536];   // [A dbuf 2x16384][B dbuf 2x16384] u16
  const int tid  = threadIdx.x;
  const int wid  = tid>>6, lane = tid&63;

  // T1: bijective chunked XCD swizzle
  const int nwg = gridDim.x;
  const int q8 = nwg>>3, r8 = nwg&7;
  const int xcd = blockIdx.x & 7, sub = blockIdx.x >> 3;
  const int wg = (xcd<r8 ? xcd*(q8+1) : r8*(q8+1)+(xcd-r8)*q8) + sub;
  const int n0 = (wg % NXT)*256;
  const int m0 = (wg / NXT)*256;

  const int wm = wid>>2, wn = wid&3;       // 2 M-waves x 4 N-waves
  const int lr = lane&15, lg = lane>>4;
  const int T  = K>>6;
  const int K64 = K<<6;                    // 64*K elements

  // staging source (pre-swizzled global columns; linear LDS dest)
  const int rg = tid>>3, g = tid&7;
  const int gswS = (g ^ (rg&7))<<3;
  const u16* gA = A + (size_t)(m0+rg)*K + gswS;
  const u16* gB = W + (size_t)(n0+rg)*K + gswS;
  const int stl = wid*512;                 // wave-uniform LDS stage base (u16)

  // ds_read swizzled group offsets (row&7 == lr&7 for all frag rows)
  const int gsw0 = ((0+lg) ^ (lr&7))<<3;
  const int gsw1 = ((4+lg) ^ (lr&7))<<3;
  const int rowA0 = wm*128 + lr;
  const int rowB0 = wn*64  + lr;

  f32x4 acc[8][4];
  #pragma unroll
  for (int i=0;i<8;i++)
    #pragma unroll
    for (int j=0;j<4;j++) acc[i][j] = (f32x4){0.f,0.f,0.f,0.f};

  bf16x8 av[2][4], bv0[2][2], bv1[2][2];

  auto STAGE = [&](const u16* ga, const u16* gb, int bufo){
    u16* la = lds + bufo + stl;
    u16* lb = lds + 32768 + bufo + stl;
    gll16(ga,        la);
    gll16(ga+K64,    la+4096);
    gll16(ga+2*K64,  la+8192);
    gll16(ga+3*K64,  la+12288);
    gll16(gb,        lb);
    gll16(gb+K64,    lb+4096);
    gll16(gb+2*K64,  lb+8192);
    gll16(gb+3*K64,  lb+12288);
  };
  auto LDA = [&](int qm, int bufo){
    #pragma unroll
    for (int i=0;i<4;i++){
      const int rb = bufo + (rowA0 + qm*64 + i*16)*64;
      av[0][i] = *(const bf16x8*)&lds[rb + gsw0];
      av[1][i] = *(const bf16x8*)&lds[rb + gsw1];
    }
  };
  auto LDB = [&](int qn, int bufo, bf16x8 (&bv)[2][2]){
    #pragma unroll
    for (int j=0;j<2;j++){
      const int rb = 32768 + bufo + (rowB0 + qn*32 + j*16)*64;
      bv[0][j] = *(const bf16x8*)&lds[rb + gsw0];
      bv[1][j] = *(const bf16x8*)&lds[rb + gsw1];
    }
  };
  auto MF = [&](int qm, int qn, bf16x8 (&bv)[2][2]){
    __builtin_amdgcn_s_setprio(1);
    #pragma unroll
    for (int kk=0;kk<2;kk++)
      #pragma unroll
      for (int i=0;i<4;i++)
        #pragma unroll
        for (int j=0;j<2;j++)
          acc[qm*4+i][qn*2+j] = __builtin_amdgcn_mfma_f32_16x16x32_bf16(
              av[kk][i], bv[kk][j], acc[qm*4+i][qn*2+j], 0,0,0);
    __builtin_amdgcn_s_setprio(0);
  };

  // prologue: stage tile 0 into buf0
  STAGE(gA, gB, 0);
  asm volatile("s_waitcnt vmcnt(0)" ::: "memory");
  __builtin_amdgcn_s_barrier();
  __builtin_amdgcn_sched_barrier(0);

  const u16* gAn = gA + 64;
  const u16* gBn = gB + 64;
  for (int t=0; t<T; ++t){
    const int bufo = (t&1)<<14;
    if (t+1 < T){
      STAGE(gAn, gBn, ((t+1)&1)<<14);
      gAn += 64; gBn += 64;
    }
    // phase 0: A0 + B0 -> quadrant (0,0)
    LDA(0, bufo); LDB(0, bufo, bv0);
    asm volatile("s_waitcnt lgkmcnt(0)" ::: "memory");
    __builtin_amdgcn_sched_barrier(0);
    MF(0,0,bv0);
    __builtin_amdgcn_s_barrier();
    // phase 1: B1 -> quadrant (0,1)
    LDB(1, bufo, bv1);
    asm volatile("s_waitcnt lgkmcnt(0)" ::: "memory");
    __builtin_amdgcn_sched_barrier(0);
    MF(0,1,bv1);
    __builtin_amdgcn_s_barrier();
    // phase 2: A1 -> quadrant (1,0)
    LDA(1, bufo);
    asm volatile("s_waitcnt lgkmcnt(0)" ::: "memory");
    __builtin_amdgcn_sched_barrier(0);
    MF(1,0,bv0);
    __builtin_amdgcn_s_barrier();
    // phase 3: quadrant (1,1)
    MF(1,1,bv1);
    // tile boundary: next tile's stage must have landed
    asm volatile("s_waitcnt vmcnt(0)" ::: "memory");
    __builtin_amdgcn_s_barrier();
    __builtin_amdgcn_sched_barrier(0);
  }

  // epilogue
  const int rbase = lg*4;
  #pragma unroll
  for (int mi=0; mi<8; mi++){
    #pragma unroll
    for (int ni=0; ni<4; ni++){
      const int col  = n0 + wn*64 + ni*16 + lr;
      const int row0 = m0 + wm*128 + mi*16 + rbase;
      const float bvl = bias[col];
      #pragma unroll
      for (int r=0;r<4;r++){
        size_t idx = (size_t)(row0+r)*N + col;
        float v = acc[mi][ni][r] + bvl;
        if (DO_ADD)  v += bf2f(add0[idx]) + bf2f(add1[idx]);
        if (DO_GELU) v = gelu_f(v);
        out[idx] = f2bf(v);
      }
    }
  }
}

// ---------------- adj contraction (and final variant): vectorized ----------------
template<int FINAL>
__global__ __launch_bounds__(512) void k_gcn2(
    const u16* __restrict__ G, const float* __restrict__ adj,
    u16* __restrict__ xg,
    const u16* __restrict__ rc, const float* __restrict__ x, int b0,
    float* __restrict__ out)
{
  __shared__ __align__(16) float adjp[51*20];
  const int tid = threadIdx.x;
  for (int i=tid; i<1020; i+=512){
    int r=i/20, cl=i%20;
    adjp[i] = (cl<17) ? adj[r*17+cl] : 0.f;
  }
  __syncthreads();

  const int sl  = tid>>7;
  const int l   = tid&127;
  const int c0  = l*4;
  const int bl  = blockIdx.x*4 + sl;

  float acc[JJ][4];
  #pragma unroll
  for (int w=0;w<JJ;w++)
    #pragma unroll
    for (int e=0;e<4;e++) acc[w][e]=0.f;

  const u16* gbase = G + (size_t)bl*JJ*1536 + c0;
  #pragma unroll 3
  for (int kv=0; kv<51; kv++){
    const int k = kv/JJ, v = kv - k*JJ;
    uint2 yu = *(const uint2*)(gbase + (size_t)v*1536 + k*512);
    float y0,y1,y2,y3;
    unpk2(yu.x, y0, y1);
    unpk2(yu.y, y2, y3);
    const f32x4* arow = (const f32x4*)&adjp[kv*20];
    f32x4 a0=arow[0], a1=arow[1], a2=arow[2], a3=arow[3];
    float a16 = adjp[kv*20+16];
    float ar[JJ] = {a0[0],a0[1],a0[2],a0[3], a1[0],a1[1],a1[2],a1[3],
                    a2[0],a2[1],a2[2],a2[3], a3[0],a3[1],a3[2],a3[3], a16};
    #pragma unroll
    for (int w=0;w<JJ;w++){
      acc[w][0] += y0*ar[w];
      acc[w][1] += y1*ar[w];
      acc[w][2] += y2*ar[w];
      acc[w][3] += y3*ar[w];
    }
  }

  if (FINAL==0){
    u16* xo = xg + (size_t)bl*JJ*CC + c0;
    #pragma unroll
    for (int w=0;w<JJ;w++){
      uint2 o;
      o.x = (uint32_t)f2bf(acc[w][0]) | ((uint32_t)f2bf(acc[w][1])<<16);
      o.y = (uint32_t)f2bf(acc[w][2]) | ((uint32_t)f2bf(acc[w][3])<<16);
      *(uint2*)(xo + (size_t)w*CC) = o;
    }
  } else {
    const size_t gb = (size_t)(b0+bl)*JJ*CC + c0;
    const u16* rp = rc + (size_t)bl*JJ*CC + c0;
    #pragma unroll
    for (int w=0;w<JJ;w++){
      uint2 ru = *(const uint2*)(rp + (size_t)w*CC);
      float r0,r1,r2,r3;
      unpk2(ru.x, r0, r1);
      unpk2(ru.y, r2, r3);
      f32x4 xv = *(const f32x4*)(x + gb + (size_t)w*CC);
      f32x4 o;
      o[0]=acc[w][0]+r0+xv[0]; o[1]=acc[w][1]+r1+xv[1];
      o[2]=acc[w][2]+r2+xv[2]; o[3]=acc[w][3]+r3+xv[3];
      *(f32x4*)(out + gb + (size_t)w*CC) = o;
    }
  }
}

// ---------------- attention over joints: one wave per head, vectorized ----------------
__global__ __launch_bounds__(512) void k_attn(const u16* __restrict__ Gqkv, u16* __restrict__ sga){
  __shared__ __align__(16) u16 qs[8*17*72];
  __shared__ __align__(16) u16 ks_[8*17*72];
  __shared__ __align__(16) float at[8*17*20];
  int b = blockIdx.x, tid = threadIdx.x;
  int h = tid>>6, d = tid&63;
  const u16* base = Gqkv + (size_t)b*JJ*1536;
  float vv[JJ];
  #pragma unroll
  for (int i=0;i<JJ;i++){
    qs [(h*JJ+i)*72 + d] = base[(size_t)i*1536 +        h*64 + d];
    ks_[(h*JJ+i)*72 + d] = base[(size_t)i*1536 +  512 + h*64 + d];
    vv[i] = bf2f(base[(size_t)i*1536 + 1024 + h*64 + d]);
  }
  __syncthreads();
  for (int p=d; p<289; p+=64){
    int i=p/JJ, j=p-i*JJ;
    const u16* qrow = &qs [(h*JJ+i)*72];
    const u16* krow = &ks_[(h*JJ+j)*72];
    float a=0.f;
    #pragma unroll
    for (int t=0;t<8;t++){
      bf16x8 q8 = *(const bf16x8*)&qrow[t*8];
      bf16x8 k8 = *(const bf16x8*)&krow[t*8];
      #pragma unroll
      for (int e=0;e<8;e++) a += (float)q8[e]*(float)k8[e];
    }
    at[(h*JJ+i)*20 + j] = a*0.125f;
  }
  __syncthreads();
  if (d < JJ){
    float* row = &at[(h*JJ+d)*20];
    f32x4 r0=((f32x4*)row)[0], r1=((f32x4*)row)[1], r2=((f32x4*)row)[2], r3=((f32x4*)row)[3];
    float e16=row[16];
    float rv[JJ]={r0[0],r0[1],r0[2],r0[3],r1[0],r1[1],r1[2],r1[3],
                  r2[0],r2[1],r2[2],r2[3],r3[0],r3[1],r3[2],r3[3],e16};
    float mx=-1e30f;
    #pragma unroll
    for (int j=0;j<JJ;j++) mx=fmaxf(mx,rv[j]);
    float sm=0.f;
    #pragma unroll
    for (int j=0;j<JJ;j++){ rv[j]=expf(rv[j]-mx); sm+=rv[j]; }
    float inv=1.f/sm;
    #pragma unroll
    for (int j=0;j<JJ;j++) row[j]=rv[j]*inv;
  }
  __syncthreads();
  #pragma unroll
  for (int i=0;i<JJ;i++){
    const float* row = &at[(h*JJ+i)*20];
    f32x4 r0=((const f32x4*)row)[0], r1=((const f32x4*)row)[1],
          r2=((const f32x4*)row)[2], r3=((const f32x4*)row)[3];
    float a = r0[0]*vv[0]+r0[1]*vv[1]+r0[2]*vv[2]+r0[3]*vv[3]
            + r1[0]*vv[4]+r1[1]*vv[5]+r1[2]*vv[6]+r1[3]*vv[7]
            + r2[0]*vv[8]+r2[1]*vv[9]+r2[2]*vv[10]+r2[3]*vv[11]
            + r3[0]*vv[12]+r3[1]*vv[13]+r3[2]*vv[14]+r3[3]*vv[15]
            + row[16]*vv[16];
    sga[((size_t)b*JJ+i)*CC + h*64 + d] = f2bf(a);
  }
}

// ---------------- token MLP: J -> TOK(gelu) -> J (padded weights, 2 ch/thread) ----------------
__global__ __launch_bounds__(512) void k_tok(const u16* __restrict__ Hpw,
    const float* __restrict__ w1p, const float* __restrict__ w2p,
    const float* __restrict__ b1, const float* __restrict__ b2,
    u16* __restrict__ h2o){
  __shared__ __align__(16) float w1s[1280], w2s[1280];
  __shared__ float b1s[64], b2s[JJ];
  const int tid = threadIdx.x;
  for (int i=tid; i<1280; i+=512){ w1s[i]=w1p[i]; w2s[i]=w2p[i]; }
  if (tid<64) b1s[tid]=b1[tid];
  if (tid<JJ) b2s[tid]=b2[tid];
  __syncthreads();

  const int bl = blockIdx.x*2 + (tid>>8);
  const int c0 = tid&255;
  const u16* hp = Hpw + (size_t)bl*JJ*CC;
  float hv0[JJ], hv1[JJ];
  #pragma unroll
  for (int j=0;j<JJ;j++){
    hv0[j]=bf2f(hp[(size_t)j*CC + c0]);
    hv1[j]=bf2f(hp[(size_t)j*CC + c0 + 256]);
  }
  float a20[JJ], a21[JJ];
  #pragma unroll
  for (int j=0;j<JJ;j++){ a20[j]=b2s[j]; a21[j]=b2s[j]; }

  for (int t=0;t<64;t++){
    float wr[20];
    *(f32x4*)&wr[0]  = *(const f32x4*)&w1s[t*20];
    *(f32x4*)&wr[4]  = *(const f32x4*)&w1s[t*20+4];
    *(f32x4*)&wr[8]  = *(const f32x4*)&w1s[t*20+8];
    *(f32x4*)&wr[12] = *(const f32x4*)&w1s[t*20+12];
    wr[16] = w1s[t*20+16];
    float a0=b1s[t], a1=b1s[t];
    #pragma unroll
    for (int j=0;j<JJ;j++){ a0 += hv0[j]*wr[j]; a1 += hv1[j]*wr[j]; }
    a0 = gelu_f(a0); a1 = gelu_f(a1);
    *(f32x4*)&wr[0]  = *(const f32x4*)&w2s[t*20];
    *(f32x4*)&wr[4]  = *(const f32x4*)&w2s[t*20+4];
    *(f32x4*)&wr[8]  = *(const f32x4*)&w2s[t*20+8];
    *(f32x4*)&wr[12] = *(const f32x4*)&w2s[t*20+12];
    wr[16] = w2s[t*20+16];
    #pragma unroll
    for (int j=0;j<JJ;j++){ a20[j] += a0*wr[j]; a21[j] += a1*wr[j]; }
  }
  u16* ho = h2o + (size_t)bl*JJ*CC;
  #pragma unroll
  for (int j=0;j<JJ;j++){
    ho[(size_t)j*CC + c0]       = f2bf(a20[j]);
    ho[(size_t)j*CC + c0 + 256] = f2bf(a21[j]);
  }
}

// ---------------- fuse: GN(gnf)+gelu -> rc ; LN(over C)(rc + x) -> xn ----------------
__global__ __launch_bounds__(512) void k_fuse(const u16* __restrict__ s,
    const float* __restrict__ x, int b0,
    const float* __restrict__ gfw, const float* __restrict__ gfb,
    const float* __restrict__ n2w, const float* __restrict__ n2b,
    u16* __restrict__ rc, u16* __restrict__ xn){
  __shared__ float rS[8][JJ], rQ[8][JJ];
  int b = blockIdx.x, c = threadIdx.x;
  int wave = c>>6, lane = c&63;
  const u16* sp = s + (size_t)b*JJ*CC + c;
  float sv[JJ];
  #pragma unroll
  for (int j=0;j<JJ;j++) sv[j]=bf2f(sp[(size_t)j*CC]);
  float ss=0.f, sq=0.f;
  #pragma unroll
  for (int j=0;j<JJ;j++){ ss+=sv[j]; sq+=sv[j]*sv[j]; }
  for (int off=32; off; off>>=1){ ss += __shfl_xor(ss,off); sq += __shfl_xor(sq,off); }
  float gm = ss*(1.f/1088.f);
  float gr = rsqrtf(sq*(1.f/1088.f) - gm*gm + 1e-5f);
  float gw=gfw[c], gb=gfb[c];
  const float* xp = x + (size_t)(b0+b)*JJ*CC + c;
  u16* rp = rc + (size_t)b*JJ*CC + c;
  float t[JJ];
  #pragma unroll
  for (int j=0;j<JJ;j++){
    float v = gelu_f((sv[j]-gm)*gr*gw + gb);
    rp[(size_t)j*CC] = f2bf(v);
    t[j] = v + xp[(size_t)j*CC];
  }
  #pragma unroll
  for (int j=0;j<JJ;j++){
    float a=t[j], q=a*a;
    for (int off=32; off; off>>=1){ a+=__shfl_xor(a,off); q+=__shfl_xor(q,off); }
    if (lane==0){ rS[wave][j]=a; rQ[wave][j]=q; }
  }
  __syncthreads();
  float wN=n2w[c], bN=n2b[c];
  u16* xo = xn + (size_t)b*JJ*CC + c;
  #pragma unroll
  for (int j=0;j<JJ;j++){
    float S=0.f,Q=0.f;
    #pragma unroll
    for (int w=0;w<8;w++){ S+=rS[w][j]; Q+=rQ[w][j]; }
    float mn=S*(1.f/512.f);
    float r2=rsqrtf(Q*(1.f/512.f)-mn*mn+1e-5f);
    xo[(size_t)j*CC]=f2bf((t[j]-mn)*r2*wN+bN);
  }
}

extern "C" void kernel_launch(void* const* d_in, const int* in_sizes, int n_in,
                              void* d_out, int out_size, void* d_ws, size_t ws_size,
                              hipStream_t stream)
{
  const float* x      = (const float*)d_in[0];
  const float* adj    = (const float*)d_in[1];
  const float* n1w    = (const float*)d_in[2];
  const float* n1b    = (const float*)d_in[3];
  const float* gcn1_w = (const float*)d_in[4];
  const float* gcn1_b = (const float*)d_in[5];
  const float* dw_w   = (const float*)d_in[6];
  const float* dw_b   = (const float*)d_in[7];
  const float* gn1_w  = (const float*)d_in[8];
  const float* gn1_b  = (const float*)d_in[9];
  const float* pw_w   = (const float*)d_in[10];
  const float* pw_b   = (const float*)d_in[11];
  const float* m1w1   = (const float*)d_in[12];
  const float* m1b1   = (const float*)d_in[13];
  const float* m1w2   = (const float*)d_in[14];
  const float* m1b2   = (const float*)d_in[15];
  const float* qkv_w  = (const float*)d_in[16];
  const float* qkv_b  = (const float*)d_in[17];
  const float* proj_w = (const float*)d_in[18];
  const float* proj_b = (const float*)d_in[19];
  const float* gnf_w  = (const float*)d_in[20];
  const float* gnf_b  = (const float*)d_in[21];
  const float* n2w    = (const float*)d_in[22];
  const float* n2b    = (const float*)d_in[23];
  const float* m2w1   = (const float*)d_in[24];
  const float* m2b1   = (const float*)d_in[25];
  const float* m2w2   = (const float*)d_in[26];
  const float* m2b2   = (const float*)d_in[27];
  const float* gcn2_w = (const float*)d_in[28];
  const float* gcn2_b = (const float*)d_in[29];
  float* out = (float*)d_out;

  char* ws = (char*)d_ws;
  const size_t WBYTES = (size_t)3932160*2;
  const size_t TPBYTES = 2560*4;

  const int cands[5] = {4096,2048,1024,512,256};
  int NB = 0;
  for (int ci=0; ci<5; ci++){
    size_t need = WBYTES + TPBYTES + (size_t)cands[ci]*JJ*2*(1536 + 4*512);
    if (need <= ws_size){ NB = cands[ci]; break; }
  }
  if (NB == 0) return;

  u16* wb = (u16*)ws;
  float* w1p = (float*)(ws + WBYTES);
  float* w2p = w1p + 1280;
  char* p = ws + WBYTES + TPBYTES;
  const size_t SZ_BIGc = (size_t)NB*JJ*1536*2;
  const size_t SZTc    = (size_t)NB*JJ*512*2;
  u16* big = (u16*)p;               p += SZ_BIGc;
  u16* t0  = (u16*)p;               p += SZTc;   // xc -> Hpw -> s -> m2
  u16* t1  = (u16*)p;               p += SZTc;   // hgn -> h2 -> rc
  u16* t2  = (u16*)p;               p += SZTc;   // xg -> xn
  u16* t3  = (u16*)p;                            // sga

  u16 *wg1=wb, *wqkv=wb+786432, *wpw=wb+1572864, *wproj=wb+1835008,
      *wm1=wb+2097152, *wm2=wb+2621440, *wg2=wb+3145728;

  k_cvt<<<(786432+255)/256,256,0,stream>>>(gcn1_w,wg1,786432);
  k_cvt<<<(786432+255)/256,256,0,stream>>>(qkv_w,wqkv,786432);
  k_cvt<<<(262144+255)/256,256,0,stream>>>(pw_w,wpw,262144);
  k_cvt<<<(262144+255)/256,256,0,stream>>>(proj_w,wproj,262144);
  k_cvt<<<(524288+255)/256,256,0,stream>>>(m2w1,wm1,524288);
  k_cvt<<<(524288+255)/256,256,0,stream>>>(m2w2,wm2,524288);
  k_cvt<<<(786432+255)/256,256,0,stream>>>(gcn2_w,wg2,786432);
  k_tokprep<<<5,256,0,stream>>>(m1w1,m1w2,w1p,w2p);

  const int M2 = NB*JJ;
  const int MT = M2/256;
  for (int b0 = 0; b0 < BB; b0 += NB){
    k_pre<<<NB,512,0,stream>>>(x,b0,n1w,n1b,dw_w,dw_b,gn1_w,gn1_b, t0/*xc*/, t1/*hgn*/);
    // GCN1
    gemm256<0,0><<<MT*6,512,0,stream>>>(t0,wg1,gcn1_b,big,nullptr,nullptr,M2,1536,512,6);
    k_gcn2<0><<<NB/4,512,0,stream>>>(big,adj,t2/*xg*/,nullptr,nullptr,0,nullptr);
    // QKV + attention
    gemm256<0,0><<<MT*6,512,0,stream>>>(t0,wqkv,qkv_b,big,nullptr,nullptr,M2,1536,512,6);
    k_attn<<<NB,512,0,stream>>>(big,t3/*sga*/);
    // pw + token MLP  (xc dead -> t0 reused for Hpw)
    gemm256<0,0><<<MT*2,512,0,stream>>>(t1,wpw,pw_b,t0/*Hpw*/,nullptr,nullptr,M2,512,512,2);
    k_tok<<<NB/2,512,0,stream>>>(t0,w1p,w2p,m1b1,m1b2,t1/*h2*/);
    // proj + branch merge: s = proj(sga)+b + xg + h2
    gemm256<0,1><<<MT*2,512,0,stream>>>(t3,wproj,proj_b,t0/*s*/,t2,t1,M2,512,512,2);
    // GN(gnf)+gelu -> rc ; LN2(rc+x) -> xn
    k_fuse<<<NB,512,0,stream>>>(t0,x,b0,gnf_w,gnf_b,n2w,n2b,t1/*rc*/,t2/*xn*/);
    // MLP2
    gemm256<1,0><<<MT*4,512,0,stream>>>(t2,wm1,m2b1,big/*m*/,nullptr,nullptr,M2,1024,512,4);
    gemm256<0,0><<<MT*2,512,0,stream>>>(big,wm2,m2b2,t0/*m2*/,nullptr,nullptr,M2,512,1024,2);
    // GCN2
    gemm256<0,0><<<MT*6,512,0,stream>>>(t0,wg2,gcn2_b,big/*G2*/,nullptr,nullptr,M2,1536,512,6);
    k_gcn2<1><<<NB/4,512,0,stream>>>(big,adj,nullptr,t1/*rc*/,x,b0,out);
  }
}

// Round 5
// 1448.736 us; speedup vs baseline: 1.4967x; 1.0481x over previous
//
#include <hip/hip_runtime.h>
#include <stdint.h>

#define BB 4096
#define JJ 17
#define CC 512

typedef unsigned short u16;
typedef __bf16 bf16x8 __attribute__((ext_vector_type(8)));
typedef float  f32x4  __attribute__((ext_vector_type(4)));
typedef float  f32x2  __attribute__((ext_vector_type(2)));

__device__ __forceinline__ float bf2f(u16 u){ return __uint_as_float(((uint32_t)u)<<16); }
__device__ __forceinline__ u16 f2bf(float f){
  uint32_t u = __float_as_uint(f);
  u += 0x7fffu + ((u>>16)&1u);           // round-to-nearest-even
  return (u16)(u>>16);
}
__device__ __forceinline__ void unpk2(uint32_t u, float& lo, float& hi){
  lo = __uint_as_float(u<<16);
  hi = __uint_as_float(u & 0xffff0000u);
}
// tanh-approx GELU: max |err| vs exact-erf ~3e-3 (threshold is 0.166)
__device__ __forceinline__ float gelu_f(float x){
  float x2 = x*x;
  float y2 = x*fmaf(0.0713548162726f, x2, 1.59576912161f);   // 2*0.79788456*(x+0.044715x^3)
  float ey = __builtin_amdgcn_exp2f(y2*1.44269504089f);      // e^{2y}
  return fmaf(-x, __builtin_amdgcn_rcpf(ey+1.f), x);         // x - x/(e^{2y}+1)
}
__device__ __forceinline__ void pkfma(f32x2& d, f32x2 a, f32x2 b){
  asm volatile("v_pk_fma_f32 %0, %1, %2, %0" : "+v"(d) : "v"(a), "v"(b));
}
__device__ __forceinline__ void gll16(const void* g, void* l){
  __builtin_amdgcn_global_load_lds(
      (const __attribute__((address_space(1))) void*)g,
      (__attribute__((address_space(3))) void*)l, 16, 0, 0);
}

// ---------------- weight f32 -> bf16 convert ----------------
__global__ void k_cvt(const float* __restrict__ in, u16* __restrict__ out, int n){
  int i = blockIdx.x*blockDim.x + threadIdx.x;
  if (i < n) out[i] = f2bf(in[i]);
}

// ---------------- token-MLP weight prep: pad rows to 20, transpose w2 ----------------
__global__ void k_tokprep(const float* __restrict__ w1, const float* __restrict__ w2,
                          float* __restrict__ w1p, float* __restrict__ w2p){
  int i = blockIdx.x*blockDim.x + threadIdx.x;     // 0..1279
  if (i >= 1280) return;
  int t = i/20, j = i%20;
  w1p[i] = (j<17) ? w1[t*17+j] : 0.f;
  w2p[i] = (j<17) ? w2[j*64+t] : 0.f;
}

// ---------------- pre: LN(over J) + dwconv + GN1 + gelu ----------------
__global__ __launch_bounds__(512) void k_pre(
    const float* __restrict__ x, int b0,
    const float* __restrict__ n1w, const float* __restrict__ n1b,
    const float* __restrict__ dww, const float* __restrict__ dwb,
    const float* __restrict__ gn1w, const float* __restrict__ gn1b,
    u16* __restrict__ xc, u16* __restrict__ hgn)
{
  int b = blockIdx.x, c = threadIdx.x;
  const float* xp = x + (size_t)(b0+b)*JJ*CC + c;
  float v[JJ]; float s = 0.f;
  #pragma unroll
  for (int j=0;j<JJ;j++){ v[j] = xp[(size_t)j*CC]; s += v[j]; }
  float mn = s*(1.f/JJ); float var = 0.f;
  #pragma unroll
  for (int j=0;j<JJ;j++){ float d=v[j]-mn; var += d*d; }
  float rr = rsqrtf(var*(1.f/JJ)+1e-5f);
  float xcv[JJ];
  #pragma unroll
  for (int j=0;j<JJ;j++) xcv[j] = (v[j]-mn)*rr*n1w[j] + n1b[j];
  u16* xo = xc + (size_t)b*JJ*CC + c;
  #pragma unroll
  for (int j=0;j<JJ;j++) xo[(size_t)j*CC] = f2bf(xcv[j]);
  float w0=dww[c*3+0], w1=dww[c*3+1], w2=dww[c*3+2], db=dwb[c];
  float h[JJ];
  #pragma unroll
  for (int j=0;j<JJ;j++){
    float a = db + w1*xcv[j];
    if (j>0)    a += w0*xcv[j-1];
    if (j<JJ-1) a += w2*xcv[j+1];
    h[j] = a;
  }
  float ss=0.f, sq=0.f;
  #pragma unroll
  for (int j=0;j<JJ;j++){ ss += h[j]; sq += h[j]*h[j]; }
  for (int off=32; off; off>>=1){ ss += __shfl_xor(ss,off); sq += __shfl_xor(sq,off); }
  float gm = ss*(1.f/(64.f*JJ));
  float gr = rsqrtf(sq*(1.f/(64.f*JJ)) - gm*gm + 1e-5f);
  float gw = gn1w[c], gb = gn1b[c];
  u16* ho = hgn + (size_t)b*JJ*CC + c;
  #pragma unroll
  for (int j=0;j<JJ;j++){
    float t = (h[j]-gm)*gr*gw + gb;
    ho[(size_t)j*CC] = f2bf(gelu_f(t));
  }
}

// ---------------- 256x256x64 8-wave pipelined MFMA GEMM ----------------
template<int DO_GELU, int DO_ADD>
__global__ __launch_bounds__(512,2) void gemm256(
    const u16* __restrict__ A, const u16* __restrict__ W, const float* __restrict__ bias,
    u16* __restrict__ out, const u16* __restrict__ add0, const u16* __restrict__ add1,
    int M, int N, int K, int NXT)
{
  __shared__ __align__(16) u16 lds[65536];
  const int tid  = threadIdx.x;
  const int wid  = tid>>6, lane = tid&63;

  const int nwg = gridDim.x;
  const int q8 = nwg>>3, r8 = nwg&7;
  const int xcd = blockIdx.x & 7, sub = blockIdx.x >> 3;
  const int wg = (xcd<r8 ? xcd*(q8+1) : r8*(q8+1)+(xcd-r8)*q8) + sub;
  const int n0 = (wg % NXT)*256;
  const int m0 = (wg / NXT)*256;

  const int wm = wid>>2, wn = wid&3;
  const int lr = lane&15, lg = lane>>4;
  const int T  = K>>6;
  const int K64 = K<<6;

  const int rg = tid>>3, g = tid&7;
  const int gswS = (g ^ (rg&7))<<3;
  const u16* gA = A + (size_t)(m0+rg)*K + gswS;
  const u16* gB = W + (size_t)(n0+rg)*K + gswS;
  const int stl = wid*512;

  const int gsw0 = ((0+lg) ^ (lr&7))<<3;
  const int gsw1 = ((4+lg) ^ (lr&7))<<3;
  const int rowA0 = wm*128 + lr;
  const int rowB0 = wn*64  + lr;

  f32x4 acc[8][4];
  #pragma unroll
  for (int i=0;i<8;i++)
    #pragma unroll
    for (int j=0;j<4;j++) acc[i][j] = (f32x4){0.f,0.f,0.f,0.f};

  bf16x8 av[2][4], bv0[2][2], bv1[2][2];

  auto STAGE = [&](const u16* ga, const u16* gb, int bufo){
    u16* la = lds + bufo + stl;
    u16* lb = lds + 32768 + bufo + stl;
    gll16(ga,        la);
    gll16(ga+K64,    la+4096);
    gll16(ga+2*K64,  la+8192);
    gll16(ga+3*K64,  la+12288);
    gll16(gb,        lb);
    gll16(gb+K64,    lb+4096);
    gll16(gb+2*K64,  lb+8192);
    gll16(gb+3*K64,  lb+12288);
  };
  auto LDA = [&](int qm, int bufo){
    #pragma unroll
    for (int i=0;i<4;i++){
      const int rb = bufo + (rowA0 + qm*64 + i*16)*64;
      av[0][i] = *(const bf16x8*)&lds[rb + gsw0];
      av[1][i] = *(const bf16x8*)&lds[rb + gsw1];
    }
  };
  auto LDB = [&](int qn, int bufo, bf16x8 (&bv)[2][2]){
    #pragma unroll
    for (int j=0;j<2;j++){
      const int rb = 32768 + bufo + (rowB0 + qn*32 + j*16)*64;
      bv[0][j] = *(const bf16x8*)&lds[rb + gsw0];
      bv[1][j] = *(const bf16x8*)&lds[rb + gsw1];
    }
  };
  auto MF = [&](int qm, int qn, bf16x8 (&bv)[2][2]){
    __builtin_amdgcn_s_setprio(1);
    #pragma unroll
    for (int kk=0;kk<2;kk++)
      #pragma unroll
      for (int i=0;i<4;i++)
        #pragma unroll
        for (int j=0;j<2;j++)
          acc[qm*4+i][qn*2+j] = __builtin_amdgcn_mfma_f32_16x16x32_bf16(
              av[kk][i], bv[kk][j], acc[qm*4+i][qn*2+j], 0,0,0);
    __builtin_amdgcn_s_setprio(0);
  };

  STAGE(gA, gB, 0);
  asm volatile("s_waitcnt vmcnt(0)" ::: "memory");
  __builtin_amdgcn_s_barrier();
  __builtin_amdgcn_sched_barrier(0);

  const u16* gAn = gA + 64;
  const u16* gBn = gB + 64;
  for (int t=0; t<T; ++t){
    const int bufo = (t&1)<<14;
    if (t+1 < T){
      STAGE(gAn, gBn, ((t+1)&1)<<14);
      gAn += 64; gBn += 64;
    }
    LDA(0, bufo); LDB(0, bufo, bv0);
    asm volatile("s_waitcnt lgkmcnt(0)" ::: "memory");
    __builtin_amdgcn_sched_barrier(0);
    MF(0,0,bv0);
    __builtin_amdgcn_s_barrier();
    LDB(1, bufo, bv1);
    asm volatile("s_waitcnt lgkmcnt(0)" ::: "memory");
    __builtin_amdgcn_sched_barrier(0);
    MF(0,1,bv1);
    __builtin_amdgcn_s_barrier();
    LDA(1, bufo);
    asm volatile("s_waitcnt lgkmcnt(0)" ::: "memory");
    __builtin_amdgcn_sched_barrier(0);
    MF(1,0,bv0);
    __builtin_amdgcn_s_barrier();
    MF(1,1,bv1);
    asm volatile("s_waitcnt vmcnt(0)" ::: "memory");
    __builtin_amdgcn_s_barrier();
    __builtin_amdgcn_sched_barrier(0);
  }

  const int rbase = lg*4;
  #pragma unroll
  for (int mi=0; mi<8; mi++){
    #pragma unroll
    for (int ni=0; ni<4; ni++){
      const int col  = n0 + wn*64 + ni*16 + lr;
      const int row0 = m0 + wm*128 + mi*16 + rbase;
      const float bvl = bias[col];
      #pragma unroll
      for (int r=0;r<4;r++){
        size_t idx = (size_t)(row0+r)*N + col;
        float v = acc[mi][ni][r] + bvl;
        if (DO_ADD)  v += bf2f(add0[idx]) + bf2f(add1[idx]);
        if (DO_GELU) v = gelu_f(v);
        out[idx] = f2bf(v);
      }
    }
  }
}

// ---------------- adj contraction (and final variant): vectorized ----------------
template<int FINAL>
__global__ __launch_bounds__(512) void k_gcn2(
    const u16* __restrict__ G, const float* __restrict__ adj,
    u16* __restrict__ xg,
    const u16* __restrict__ rc, const float* __restrict__ x, int b0,
    float* __restrict__ out)
{
  __shared__ __align__(16) float adjp[51*20];
  const int tid = threadIdx.x;
  for (int i=tid; i<1020; i+=512){
    int r=i/20, cl=i%20;
    adjp[i] = (cl<17) ? adj[r*17+cl] : 0.f;
  }
  __syncthreads();

  const int sl  = tid>>7;
  const int l   = tid&127;
  const int c0  = l*4;
  const int bl  = blockIdx.x*4 + sl;

  float acc[JJ][4];
  #pragma unroll
  for (int w=0;w<JJ;w++)
    #pragma unroll
    for (int e=0;e<4;e++) acc[w][e]=0.f;

  const u16* gbase = G + (size_t)bl*JJ*1536 + c0;
  #pragma unroll 3
  for (int kv=0; kv<51; kv++){
    const int k = kv/JJ, v = kv - k*JJ;
    uint2 yu = *(const uint2*)(gbase + (size_t)v*1536 + k*512);
    float y0,y1,y2,y3;
    unpk2(yu.x, y0, y1);
    unpk2(yu.y, y2, y3);
    const f32x4* arow = (const f32x4*)&adjp[kv*20];
    f32x4 a0=arow[0], a1=arow[1], a2=arow[2], a3=arow[3];
    float a16 = adjp[kv*20+16];
    float ar[JJ] = {a0[0],a0[1],a0[2],a0[3], a1[0],a1[1],a1[2],a1[3],
                    a2[0],a2[1],a2[2],a2[3], a3[0],a3[1],a3[2],a3[3], a16};
    #pragma unroll
    for (int w=0;w<JJ;w++){
      acc[w][0] += y0*ar[w];
      acc[w][1] += y1*ar[w];
      acc[w][2] += y2*ar[w];
      acc[w][3] += y3*ar[w];
    }
  }

  if (FINAL==0){
    u16* xo = xg + (size_t)bl*JJ*CC + c0;
    #pragma unroll
    for (int w=0;w<JJ;w++){
      uint2 o;
      o.x = (uint32_t)f2bf(acc[w][0]) | ((uint32_t)f2bf(acc[w][1])<<16);
      o.y = (uint32_t)f2bf(acc[w][2]) | ((uint32_t)f2bf(acc[w][3])<<16);
      *(uint2*)(xo + (size_t)w*CC) = o;
    }
  } else {
    const size_t gb = (size_t)(b0+bl)*JJ*CC + c0;
    const u16* rp = rc + (size_t)bl*JJ*CC + c0;
    #pragma unroll
    for (int w=0;w<JJ;w++){
      uint2 ru = *(const uint2*)(rp + (size_t)w*CC);
      float r0,r1,r2,r3;
      unpk2(ru.x, r0, r1);
      unpk2(ru.y, r2, r3);
      f32x4 xv = *(const f32x4*)(x + gb + (size_t)w*CC);
      f32x4 o;
      o[0]=acc[w][0]+r0+xv[0]; o[1]=acc[w][1]+r1+xv[1];
      o[2]=acc[w][2]+r2+xv[2]; o[3]=acc[w][3]+r3+xv[3];
      *(f32x4*)(out + gb + (size_t)w*CC) = o;
    }
  }
}

// ---------------- attention over joints: one wave per head, vectorized ----------------
__global__ __launch_bounds__(512) void k_attn(const u16* __restrict__ Gqkv, u16* __restrict__ sga){
  __shared__ __align__(16) u16 qs[8*17*72];
  __shared__ __align__(16) u16 ks_[8*17*72];
  __shared__ __align__(16) float at[8*17*20];
  int b = blockIdx.x, tid = threadIdx.x;
  int h = tid>>6, d = tid&63;
  const u16* base = Gqkv + (size_t)b*JJ*1536;
  float vv[JJ];
  #pragma unroll
  for (int i=0;i<JJ;i++){
    qs [(h*JJ+i)*72 + d] = base[(size_t)i*1536 +        h*64 + d];
    ks_[(h*JJ+i)*72 + d] = base[(size_t)i*1536 +  512 + h*64 + d];
    vv[i] = bf2f(base[(size_t)i*1536 + 1024 + h*64 + d]);
  }
  __syncthreads();
  for (int p=d; p<289; p+=64){
    int i=p/JJ, j=p-i*JJ;
    const u16* qrow = &qs [(h*JJ+i)*72];
    const u16* krow = &ks_[(h*JJ+j)*72];
    float a=0.f;
    #pragma unroll
    for (int t=0;t<8;t++){
      bf16x8 q8 = *(const bf16x8*)&qrow[t*8];
      bf16x8 k8 = *(const bf16x8*)&krow[t*8];
      #pragma unroll
      for (int e=0;e<8;e++) a += (float)q8[e]*(float)k8[e];
    }
    at[(h*JJ+i)*20 + j] = a*0.125f;
  }
  __syncthreads();
  if (d < JJ){
    float* row = &at[(h*JJ+d)*20];
    f32x4 r0=((f32x4*)row)[0], r1=((f32x4*)row)[1], r2=((f32x4*)row)[2], r3=((f32x4*)row)[3];
    float e16=row[16];
    float rv[JJ]={r0[0],r0[1],r0[2],r0[3],r1[0],r1[1],r1[2],r1[3],
                  r2[0],r2[1],r2[2],r2[3],r3[0],r3[1],r3[2],r3[3],e16};
    float mx=-1e30f;
    #pragma unroll
    for (int j=0;j<JJ;j++) mx=fmaxf(mx,rv[j]);
    float sm=0.f;
    #pragma unroll
    for (int j=0;j<JJ;j++){ rv[j]=__builtin_amdgcn_exp2f((rv[j]-mx)*1.44269504089f); sm+=rv[j]; }
    float inv=1.f/sm;
    #pragma unroll
    for (int j=0;j<JJ;j++) row[j]=rv[j]*inv;
  }
  __syncthreads();
  #pragma unroll
  for (int i=0;i<JJ;i++){
    const float* row = &at[(h*JJ+i)*20];
    f32x4 r0=((const f32x4*)row)[0], r1=((const f32x4*)row)[1],
          r2=((const f32x4*)row)[2], r3=((const f32x4*)row)[3];
    float a = r0[0]*vv[0]+r0[1]*vv[1]+r0[2]*vv[2]+r0[3]*vv[3]
            + r1[0]*vv[4]+r1[1]*vv[5]+r1[2]*vv[6]+r1[3]*vv[7]
            + r2[0]*vv[8]+r2[1]*vv[9]+r2[2]*vv[10]+r2[3]*vv[11]
            + r3[0]*vv[12]+r3[1]*vv[13]+r3[2]*vv[14]+r3[3]*vv[15]
            + row[16]*vv[16];
    sga[((size_t)b*JJ+i)*CC + h*64 + d] = f2bf(a);
  }
}

// ---------------- token MLP: J -> TOK(gelu) -> J, packed-fp32 FMA ----------------
__global__ __launch_bounds__(512) void k_tok(const u16* __restrict__ Hpw,
    const float* __restrict__ w1p, const float* __restrict__ w2p,
    const float* __restrict__ b1, const float* __restrict__ b2,
    u16* __restrict__ h2o){
  __shared__ __align__(16) float w1s[1280], w2s[1280];
  __shared__ float b1s[64], b2s[20];
  const int tid = threadIdx.x;
  for (int i=tid; i<1280; i+=512){ w1s[i]=w1p[i]; w2s[i]=w2p[i]; }
  if (tid<64) b1s[tid]=b1[tid];
  if (tid<20) b2s[tid] = (tid<17) ? b2[tid] : 0.f;
  __syncthreads();

  const int bl = blockIdx.x*2 + (tid>>8);
  const int c0 = tid&255;
  const u16* hp = Hpw + (size_t)bl*JJ*CC;
  float hv0[JJ], hv1[JJ];
  #pragma unroll
  for (int j=0;j<JJ;j++){
    hv0[j]=bf2f(hp[(size_t)j*CC + c0]);
    hv1[j]=bf2f(hp[(size_t)j*CC + c0 + 256]);
  }
  f32x2 h0p[9], h1p[9];
  #pragma unroll
  for (int p=0;p<8;p++){
    h0p[p] = (f32x2){hv0[2*p], hv0[2*p+1]};
    h1p[p] = (f32x2){hv1[2*p], hv1[2*p+1]};
  }
  h0p[8] = (f32x2){hv0[16], 0.f};
  h1p[8] = (f32x2){hv1[16], 0.f};

  f32x2 a20[9], a21[9];
  #pragma unroll
  for (int p=0;p<9;p++){
    f32x2 bb = (f32x2){b2s[2*p], b2s[2*p+1]};
    a20[p]=bb; a21[p]=bb;
  }

  for (int t=0;t<64;t++){
    f32x4 wa = *(const f32x4*)&w1s[t*20];
    f32x4 wb = *(const f32x4*)&w1s[t*20+4];
    f32x4 wc = *(const f32x4*)&w1s[t*20+8];
    f32x4 wd = *(const f32x4*)&w1s[t*20+12];
    float  we = w1s[t*20+16];
    f32x2 wp[9] = {(f32x2){wa[0],wa[1]},(f32x2){wa[2],wa[3]},
                   (f32x2){wb[0],wb[1]},(f32x2){wb[2],wb[3]},
                   (f32x2){wc[0],wc[1]},(f32x2){wc[2],wc[3]},
                   (f32x2){wd[0],wd[1]},(f32x2){wd[2],wd[3]},
                   (f32x2){we,0.f}};
    f32x2 s0 = (f32x2){b1s[t], 0.f};
    f32x2 s1 = s0;
    #pragma unroll
    for (int p=0;p<9;p++){ pkfma(s0, h0p[p], wp[p]); pkfma(s1, h1p[p], wp[p]); }
    float a0 = gelu_f(s0[0] + s0[1]);
    float a1 = gelu_f(s1[0] + s1[1]);
    wa = *(const f32x4*)&w2s[t*20];
    wb = *(const f32x4*)&w2s[t*20+4];
    wc = *(const f32x4*)&w2s[t*20+8];
    wd = *(const f32x4*)&w2s[t*20+12];
    we = w2s[t*20+16];
    f32x2 wq[9] = {(f32x2){wa[0],wa[1]},(f32x2){wa[2],wa[3]},
                   (f32x2){wb[0],wb[1]},(f32x2){wb[2],wb[3]},
                   (f32x2){wc[0],wc[1]},(f32x2){wc[2],wc[3]},
                   (f32x2){wd[0],wd[1]},(f32x2){wd[2],wd[3]},
                   (f32x2){we,0.f}};
    f32x2 a0b = (f32x2){a0,a0};
    f32x2 a1b = (f32x2){a1,a1};
    #pragma unroll
    for (int p=0;p<9;p++){ pkfma(a20[p], a0b, wq[p]); pkfma(a21[p], a1b, wq[p]); }
  }
  u16* ho = h2o + (size_t)bl*JJ*CC;
  #pragma unroll
  for (int j=0;j<JJ;j++){
    ho[(size_t)j*CC + c0]       = f2bf(a20[j>>1][j&1]);
    ho[(size_t)j*CC + c0 + 256] = f2bf(a21[j>>1][j&1]);
  }
}

// ---------------- fuse: GN(gnf)+gelu -> rc ; LN(over C)(rc + x) -> xn ----------------
__global__ __launch_bounds__(512) void k_fuse(const u16* __restrict__ s,
    const float* __restrict__ x, int b0,
    const float* __restrict__ gfw, const float* __restrict__ gfb,
    const float* __restrict__ n2w, const float* __restrict__ n2b,
    u16* __restrict__ rc, u16* __restrict__ xn){
  __shared__ float rS[8][JJ], rQ[8][JJ];
  int b = blockIdx.x, c = threadIdx.x;
  int wave = c>>6, lane = c&63;
  const u16* sp = s + (size_t)b*JJ*CC + c;
  float sv[JJ];
  #pragma unroll
  for (int j=0;j<JJ;j++) sv[j]=bf2f(sp[(size_t)j*CC]);
  float ss=0.f, sq=0.f;
  #pragma unroll
  for (int j=0;j<JJ;j++){ ss+=sv[j]; sq+=sv[j]*sv[j]; }
  for (int off=32; off; off>>=1){ ss += __shfl_xor(ss,off); sq += __shfl_xor(sq,off); }
  float gm = ss*(1.f/1088.f);
  float gr = rsqrtf(sq*(1.f/1088.f) - gm*gm + 1e-5f);
  float gw=gfw[c], gb=gfb[c];
  const float* xp = x + (size_t)(b0+b)*JJ*CC + c;
  u16* rp = rc + (size_t)b*JJ*CC + c;
  float t[JJ];
  #pragma unroll
  for (int j=0;j<JJ;j++){
    float v = gelu_f((sv[j]-gm)*gr*gw + gb);
    rp[(size_t)j*CC] = f2bf(v);
    t[j] = v + xp[(size_t)j*CC];
  }
  #pragma unroll
  for (int j=0;j<JJ;j++){
    float a=t[j], q=a*a;
    for (int off=32; off; off>>=1){ a+=__shfl_xor(a,off); q+=__shfl_xor(q,off); }
    if (lane==0){ rS[wave][j]=a; rQ[wave][j]=q; }
  }
  __syncthreads();
  float wN=n2w[c], bN=n2b[c];
  u16* xo = xn + (size_t)b*JJ*CC + c;
  #pragma unroll
  for (int j=0;j<JJ;j++){
    float S=0.f,Q=0.f;
    #pragma unroll
    for (int w=0;w<8;w++){ S+=rS[w][j]; Q+=rQ[w][j]; }
    float mn=S*(1.f/512.f);
    float r2=rsqrtf(Q*(1.f/512.f)-mn*mn+1e-5f);
    xo[(size_t)j*CC]=f2bf((t[j]-mn)*r2*wN+bN);
  }
}

extern "C" void kernel_launch(void* const* d_in, const int* in_sizes, int n_in,
                              void* d_out, int out_size, void* d_ws, size_t ws_size,
                              hipStream_t stream)
{
  const float* x      = (const float*)d_in[0];
  const float* adj    = (const float*)d_in[1];
  const float* n1w    = (const float*)d_in[2];
  const float* n1b    = (const float*)d_in[3];
  const float* gcn1_w = (const float*)d_in[4];
  const float* gcn1_b = (const float*)d_in[5];
  const float* dw_w   = (const float*)d_in[6];
  const float* dw_b   = (const float*)d_in[7];
  const float* gn1_w  = (const float*)d_in[8];
  const float* gn1_b  = (const float*)d_in[9];
  const float* pw_w   = (const float*)d_in[10];
  const float* pw_b   = (const float*)d_in[11];
  const float* m1w1   = (const float*)d_in[12];
  const float* m1b1   = (const float*)d_in[13];
  const float* m1w2   = (const float*)d_in[14];
  const float* m1b2   = (const float*)d_in[15];
  const float* qkv_w  = (const float*)d_in[16];
  const float* qkv_b  = (const float*)d_in[17];
  const float* proj_w = (const float*)d_in[18];
  const float* proj_b = (const float*)d_in[19];
  const float* gnf_w  = (const float*)d_in[20];
  const float* gnf_b  = (const float*)d_in[21];
  const float* n2w    = (const float*)d_in[22];
  const float* n2b    = (const float*)d_in[23];
  const float* m2w1   = (const float*)d_in[24];
  const float* m2b1   = (const float*)d_in[25];
  const float* m2w2   = (const float*)d_in[26];
  const float* m2b2   = (const float*)d_in[27];
  const float* gcn2_w = (const float*)d_in[28];
  const float* gcn2_b = (const float*)d_in[29];
  float* out = (float*)d_out;

  char* ws = (char*)d_ws;
  const size_t WBYTES = (size_t)3932160*2;
  const size_t TPBYTES = 2560*4;

  const int cands[5] = {4096,2048,1024,512,256};
  int NB = 0;
  for (int ci=0; ci<5; ci++){
    size_t need = WBYTES + TPBYTES + (size_t)cands[ci]*JJ*2*(1536 + 4*512);
    if (need <= ws_size){ NB = cands[ci]; break; }
  }
  if (NB == 0) return;

  u16* wb = (u16*)ws;
  float* w1p = (float*)(ws + WBYTES);
  float* w2p = w1p + 1280;
  char* p = ws + WBYTES + TPBYTES;
  const size_t SZ_BIGc = (size_t)NB*JJ*1536*2;
  const size_t SZTc    = (size_t)NB*JJ*512*2;
  u16* big = (u16*)p;               p += SZ_BIGc;
  u16* t0  = (u16*)p;               p += SZTc;   // xc -> Hpw -> s -> m2
  u16* t1  = (u16*)p;               p += SZTc;   // hgn -> h2 -> rc
  u16* t2  = (u16*)p;               p += SZTc;   // xg -> xn
  u16* t3  = (u16*)p;                            // sga

  u16 *wg1=wb, *wqkv=wb+786432, *wpw=wb+1572864, *wproj=wb+1835008,
      *wm1=wb+2097152, *wm2=wb+2621440, *wg2=wb+3145728;

  k_cvt<<<(786432+255)/256,256,0,stream>>>(gcn1_w,wg1,786432);
  k_cvt<<<(786432+255)/256,256,0,stream>>>(qkv_w,wqkv,786432);
  k_cvt<<<(262144+255)/256,256,0,stream>>>(pw_w,wpw,262144);
  k_cvt<<<(262144+255)/256,256,0,stream>>>(proj_w,wproj,262144);
  k_cvt<<<(524288+255)/256,256,0,stream>>>(m2w1,wm1,524288);
  k_cvt<<<(524288+255)/256,256,0,stream>>>(m2w2,wm2,524288);
  k_cvt<<<(786432+255)/256,256,0,stream>>>(gcn2_w,wg2,786432);
  k_tokprep<<<5,256,0,stream>>>(m1w1,m1w2,w1p,w2p);

  const int M2 = NB*JJ;
  const int MT = M2/256;
  for (int b0 = 0; b0 < BB; b0 += NB){
    k_pre<<<NB,512,0,stream>>>(x,b0,n1w,n1b,dw_w,dw_b,gn1_w,gn1_b, t0/*xc*/, t1/*hgn*/);
    // GCN1
    gemm256<0,0><<<MT*6,512,0,stream>>>(t0,wg1,gcn1_b,big,nullptr,nullptr,M2,1536,512,6);
    k_gcn2<0><<<NB/4,512,0,stream>>>(big,adj,t2/*xg*/,nullptr,nullptr,0,nullptr);
    // QKV + attention
    gemm256<0,0><<<MT*6,512,0,stream>>>(t0,wqkv,qkv_b,big,nullptr,nullptr,M2,1536,512,6);
    k_attn<<<NB,512,0,stream>>>(big,t3/*sga*/);
    // pw + token MLP  (xc dead -> t0 reused for Hpw)
    gemm256<0,0><<<MT*2,512,0,stream>>>(t1,wpw,pw_b,t0/*Hpw*/,nullptr,nullptr,M2,512,512,2);
    k_tok<<<NB/2,512,0,stream>>>(t0,w1p,w2p,m1b1,m1b2,t1/*h2*/);
    // proj + branch merge: s = proj(sga)+b + xg + h2
    gemm256<0,1><<<MT*2,512,0,stream>>>(t3,wproj,proj_b,t0/*s*/,t2,t1,M2,512,512,2);
    // GN(gnf)+gelu -> rc ; LN2(rc+x) -> xn
    k_fuse<<<NB,512,0,stream>>>(t0,x,b0,gnf_w,gnf_b,n2w,n2b,t1/*rc*/,t2/*xn*/);
    // MLP2
    gemm256<1,0><<<MT*4,512,0,stream>>>(t2,wm1,m2b1,big/*m*/,nullptr,nullptr,M2,1024,512,4);
    gemm256<0,0><<<MT*2,512,0,stream>>>(big,wm2,m2b2,t0/*m2*/,nullptr,nullptr,M2,512,1024,2);
    // GCN2
    gemm256<0,0><<<MT*6,512,0,stream>>>(t0,wg2,gcn2_b,big/*G2*/,nullptr,nullptr,M2,1536,512,6);
    k_gcn2<1><<<NB/4,512,0,stream>>>(big,adj,nullptr,t1/*rc*/,x,b0,out);
  }
}

// Round 6
// 1419.889 us; speedup vs baseline: 1.5271x; 1.0203x over previous
//
#include <hip/hip_runtime.h>
#include <stdint.h>

#define BB 4096
#define JJ 17
#define CC 512

typedef unsigned short u16;
typedef __bf16 bf16x8 __attribute__((ext_vector_type(8)));
typedef float  f32x4  __attribute__((ext_vector_type(4)));
typedef float  f32x2  __attribute__((ext_vector_type(2)));

__device__ __forceinline__ float bf2f(u16 u){ return __uint_as_float(((uint32_t)u)<<16); }
__device__ __forceinline__ u16 f2bf(float f){
  uint32_t u = __float_as_uint(f);
  u += 0x7fffu + ((u>>16)&1u);           // round-to-nearest-even
  return (u16)(u>>16);
}
__device__ __forceinline__ void unpk2(uint32_t u, float& lo, float& hi){
  lo = __uint_as_float(u<<16);
  hi = __uint_as_float(u & 0xffff0000u);
}
// tanh-approx GELU: max |err| vs exact-erf ~3e-3 (threshold is 0.166)
__device__ __forceinline__ float gelu_f(float x){
  float x2 = x*x;
  float y2 = x*fmaf(0.0713548162726f, x2, 1.59576912161f);
  float ey = __builtin_amdgcn_exp2f(y2*1.44269504089f);
  return fmaf(-x, __builtin_amdgcn_rcpf(ey+1.f), x);
}
__device__ __forceinline__ void pkfma(f32x2& d, f32x2 a, f32x2 b){
  asm volatile("v_pk_fma_f32 %0, %1, %2, %0" : "+v"(d) : "v"(a), "v"(b));
}
__device__ __forceinline__ void gll16(const void* g, void* l){
  __builtin_amdgcn_global_load_lds(
      (const __attribute__((address_space(1))) void*)g,
      (__attribute__((address_space(3))) void*)l, 16, 0, 0);
}

// ---------------- weight f32 -> bf16 convert ----------------
__global__ void k_cvt(const float* __restrict__ in, u16* __restrict__ out, int n){
  int i = blockIdx.x*blockDim.x + threadIdx.x;
  if (i < n) out[i] = f2bf(in[i]);
}

// ---------------- token-MLP weight prep ----------------
__global__ void k_tokprep(const float* __restrict__ w1, const float* __restrict__ w2,
                          float* __restrict__ w1p, float* __restrict__ w2p){
  int i = blockIdx.x*blockDim.x + threadIdx.x;
  if (i >= 1280) return;
  int t = i/20, j = i%20;
  w1p[i] = (j<17) ? w1[t*17+j] : 0.f;
  w2p[i] = (j<17) ? w2[j*64+t] : 0.f;
}

// ---------------- pre: LN(over J) + dwconv + GN1 + gelu ----------------
__global__ __launch_bounds__(512) void k_pre(
    const float* __restrict__ x, int b0,
    const float* __restrict__ n1w, const float* __restrict__ n1b,
    const float* __restrict__ dww, const float* __restrict__ dwb,
    const float* __restrict__ gn1w, const float* __restrict__ gn1b,
    u16* __restrict__ xc, u16* __restrict__ hgn)
{
  int b = blockIdx.x, c = threadIdx.x;
  const float* xp = x + (size_t)(b0+b)*JJ*CC + c;
  float v[JJ]; float s = 0.f;
  #pragma unroll
  for (int j=0;j<JJ;j++){ v[j] = xp[(size_t)j*CC]; s += v[j]; }
  float mn = s*(1.f/JJ); float var = 0.f;
  #pragma unroll
  for (int j=0;j<JJ;j++){ float d=v[j]-mn; var += d*d; }
  float rr = rsqrtf(var*(1.f/JJ)+1e-5f);
  float xcv[JJ];
  #pragma unroll
  for (int j=0;j<JJ;j++) xcv[j] = (v[j]-mn)*rr*n1w[j] + n1b[j];
  u16* xo = xc + (size_t)b*JJ*CC + c;
  #pragma unroll
  for (int j=0;j<JJ;j++) xo[(size_t)j*CC] = f2bf(xcv[j]);
  float w0=dww[c*3+0], w1=dww[c*3+1], w2=dww[c*3+2], db=dwb[c];
  float h[JJ];
  #pragma unroll
  for (int j=0;j<JJ;j++){
    float a = db + w1*xcv[j];
    if (j>0)    a += w0*xcv[j-1];
    if (j<JJ-1) a += w2*xcv[j+1];
    h[j] = a;
  }
  float ss=0.f, sq=0.f;
  #pragma unroll
  for (int j=0;j<JJ;j++){ ss += h[j]; sq += h[j]*h[j]; }
  for (int off=32; off; off>>=1){ ss += __shfl_xor(ss,off); sq += __shfl_xor(sq,off); }
  float gm = ss*(1.f/(64.f*JJ));
  float gr = rsqrtf(sq*(1.f/(64.f*JJ)) - gm*gm + 1e-5f);
  float gw = gn1w[c], gb = gn1b[c];
  u16* ho = hgn + (size_t)b*JJ*CC + c;
  #pragma unroll
  for (int j=0;j<JJ;j++){
    float t = (h[j]-gm)*gr*gw + gb;
    ho[(size_t)j*CC] = f2bf(gelu_f(t));
  }
}

// ---------------- 128x128x32 ring-3 counted-vmcnt MFMA GEMM ----------------
// out[M,N] = A[M,K] @ W[N,K]^T (+bias)(+adds)(+gelu). M%128==0, N%128==0, K%64==0.
// LDS: 3 slots x (A[128][32] + B[128][32]) u16 = 48KB -> 3 blocks/CU.
// Counted vmcnt(4): stage(t+2) issued at step t; wait only for stage(t+1).
template<int DO_GELU, int DO_ADD>
__global__ __launch_bounds__(256,3) void gemm_r3(
    const u16* __restrict__ A, const u16* __restrict__ W, const float* __restrict__ bias,
    u16* __restrict__ out, const u16* __restrict__ add0, const u16* __restrict__ add1,
    int M, int N, int K, int NXT)
{
  __shared__ __align__(16) u16 lds[24576];
  const int tid = threadIdx.x;
  const int wid = tid>>6, lane = tid&63;

  // T1: bijective chunked XCD swizzle
  const int nwg = gridDim.x;
  const int q8 = nwg>>3, r8 = nwg&7;
  const int xcd = blockIdx.x & 7, sub = blockIdx.x >> 3;
  const int wg = (xcd<r8 ? xcd*(q8+1) : r8*(q8+1)+(xcd-r8)*q8) + sub;
  const int n0 = (wg % NXT)*128;
  const int m0 = (wg / NXT)*128;

  const int wm = wid>>1, wn = wid&1;      // 2x2 waves, 64x64 per wave
  const int lr = lane&15, lg = lane>>4;
  const int T  = K>>5;

  // staging: row=(tid>>2)+l*64, group=(tid&3)^((row>>1)&3) = (tid&3)^((tid>>3)&3)
  const int srow = tid>>2;
  const int gswS = ((tid&3) ^ ((tid>>3)&3))<<3;   // u16 offset within row
  const u16* gA = A + (size_t)(m0+srow)*K + gswS;
  const u16* gB = W + (size_t)(n0+srow)*K + gswS;
  const int K64 = K<<6;                    // 64 rows * K elements
  const int dstl = tid*8;                  // u16: linear wave dest

  // ds_read: row = base+lr, group g = lg ^ ((lr>>1)&3)  -> 2-way (free) banks
  const int g8 = (lg ^ ((lr>>1)&3))<<3;
  const int offA0 = (wm*64+lr)*32 + g8;
  const int offB0 = 4096 + (wn*64+lr)*32 + g8;

  f32x4 acc[4][4];
  #pragma unroll
  for (int i=0;i<4;i++)
    #pragma unroll
    for (int j=0;j<4;j++) acc[i][j] = (f32x4){0.f,0.f,0.f,0.f};

  auto STAGE = [&](int t, int sofs){
    const u16* ga = gA + t*32;
    const u16* gb = gB + t*32;
    u16* la = lds + sofs + dstl;
    u16* lb = lds + sofs + 4096 + dstl;
    gll16(ga,     la);
    gll16(ga+K64, la+2048);
    gll16(gb,     lb);
    gll16(gb+K64, lb+2048);
  };

  // prologue: T0 -> slot0, T1 -> slot1; wait T0 (4 newest = T1 stay in flight)
  STAGE(0, 0); STAGE(1, 8192);
  asm volatile("s_waitcnt vmcnt(4)" ::: "memory");
  __builtin_amdgcn_s_barrier();

  int s0 = 0, s1 = 8192, s2 = 16384;       // LDS u16 offsets of ring slots
  for (int t=0; t<T; ++t){
    const bool more = (t+2 < T);
    if (more) STAGE(t+2, s2);              // target slot freed at end of step t-1
    bf16x8 av[4], bv[4];
    #pragma unroll
    for (int i=0;i<4;i++) av[i] = *(const bf16x8*)&lds[s0 + offA0 + i*512];
    #pragma unroll
    for (int j=0;j<4;j++) bv[j] = *(const bf16x8*)&lds[s0 + offB0 + j*512];
    asm volatile("s_waitcnt lgkmcnt(0)" ::: "memory");
    __builtin_amdgcn_sched_barrier(0);
    __builtin_amdgcn_s_setprio(1);
    #pragma unroll
    for (int i=0;i<4;i++)
      #pragma unroll
      for (int j=0;j<4;j++)
        acc[i][j] = __builtin_amdgcn_mfma_f32_16x16x32_bf16(av[i], bv[j], acc[i][j], 0,0,0);
    __builtin_amdgcn_s_setprio(0);
    if (more) asm volatile("s_waitcnt vmcnt(4)" ::: "memory");  // stage(t+1) landed
    else      asm volatile("s_waitcnt vmcnt(0)" ::: "memory");
    __builtin_amdgcn_s_barrier();
    const int tmp = s0; s0 = s1; s1 = s2; s2 = tmp;             // rotate ring
  }

  const int rbase = lg*4;
  #pragma unroll
  for (int i=0;i<4;i++){
    #pragma unroll
    for (int j=0;j<4;j++){
      const int col  = n0 + wn*64 + j*16 + lr;
      const int row0 = m0 + wm*64 + i*16 + rbase;
      const float bvl = bias[col];
      #pragma unroll
      for (int r=0;r<4;r++){
        size_t idx = (size_t)(row0+r)*N + col;
        float v = acc[i][j][r] + bvl;
        if (DO_ADD)  v += bf2f(add0[idx]) + bf2f(add1[idx]);
        if (DO_GELU) v = gelu_f(v);
        out[idx] = f2bf(v);
      }
    }
  }
}

// ---------------- adj contraction (and final variant): vectorized ----------------
template<int FINAL>
__global__ __launch_bounds__(512) void k_gcn2(
    const u16* __restrict__ G, const float* __restrict__ adj,
    u16* __restrict__ xg,
    const u16* __restrict__ rc, const float* __restrict__ x, int b0,
    float* __restrict__ out)
{
  __shared__ __align__(16) float adjp[51*20];
  const int tid = threadIdx.x;
  for (int i=tid; i<1020; i+=512){
    int r=i/20, cl=i%20;
    adjp[i] = (cl<17) ? adj[r*17+cl] : 0.f;
  }
  __syncthreads();

  const int sl  = tid>>7;
  const int l   = tid&127;
  const int c0  = l*4;
  const int bl  = blockIdx.x*4 + sl;

  float acc[JJ][4];
  #pragma unroll
  for (int w=0;w<JJ;w++)
    #pragma unroll
    for (int e=0;e<4;e++) acc[w][e]=0.f;

  const u16* gbase = G + (size_t)bl*JJ*1536 + c0;
  #pragma unroll 3
  for (int kv=0; kv<51; kv++){
    const int k = kv/JJ, v = kv - k*JJ;
    uint2 yu = *(const uint2*)(gbase + (size_t)v*1536 + k*512);
    float y0,y1,y2,y3;
    unpk2(yu.x, y0, y1);
    unpk2(yu.y, y2, y3);
    const f32x4* arow = (const f32x4*)&adjp[kv*20];
    f32x4 a0=arow[0], a1=arow[1], a2=arow[2], a3=arow[3];
    float a16 = adjp[kv*20+16];
    float ar[JJ] = {a0[0],a0[1],a0[2],a0[3], a1[0],a1[1],a1[2],a1[3],
                    a2[0],a2[1],a2[2],a2[3], a3[0],a3[1],a3[2],a3[3], a16};
    #pragma unroll
    for (int w=0;w<JJ;w++){
      acc[w][0] += y0*ar[w];
      acc[w][1] += y1*ar[w];
      acc[w][2] += y2*ar[w];
      acc[w][3] += y3*ar[w];
    }
  }

  if (FINAL==0){
    u16* xo = xg + (size_t)bl*JJ*CC + c0;
    #pragma unroll
    for (int w=0;w<JJ;w++){
      uint2 o;
      o.x = (uint32_t)f2bf(acc[w][0]) | ((uint32_t)f2bf(acc[w][1])<<16);
      o.y = (uint32_t)f2bf(acc[w][2]) | ((uint32_t)f2bf(acc[w][3])<<16);
      *(uint2*)(xo + (size_t)w*CC) = o;
    }
  } else {
    const size_t gb = (size_t)(b0+bl)*JJ*CC + c0;
    const u16* rp = rc + (size_t)bl*JJ*CC + c0;
    #pragma unroll
    for (int w=0;w<JJ;w++){
      uint2 ru = *(const uint2*)(rp + (size_t)w*CC);
      float r0,r1,r2,r3;
      unpk2(ru.x, r0, r1);
      unpk2(ru.y, r2, r3);
      f32x4 xv = *(const f32x4*)(x + gb + (size_t)w*CC);
      f32x4 o;
      o[0]=acc[w][0]+r0+xv[0]; o[1]=acc[w][1]+r1+xv[1];
      o[2]=acc[w][2]+r2+xv[2]; o[3]=acc[w][3]+r3+xv[3];
      *(f32x4*)(out + gb + (size_t)w*CC) = o;
    }
  }
}

// ---------------- attention over joints: one wave per head, vectorized ----------------
__global__ __launch_bounds__(512) void k_attn(const u16* __restrict__ Gqkv, u16* __restrict__ sga){
  __shared__ __align__(16) u16 qs[8*17*72];
  __shared__ __align__(16) u16 ks_[8*17*72];
  __shared__ __align__(16) float at[8*17*20];
  int b = blockIdx.x, tid = threadIdx.x;
  int h = tid>>6, d = tid&63;
  const u16* base = Gqkv + (size_t)b*JJ*1536;
  float vv[JJ];
  #pragma unroll
  for (int i=0;i<JJ;i++){
    qs [(h*JJ+i)*72 + d] = base[(size_t)i*1536 +        h*64 + d];
    ks_[(h*JJ+i)*72 + d] = base[(size_t)i*1536 +  512 + h*64 + d];
    vv[i] = bf2f(base[(size_t)i*1536 + 1024 + h*64 + d]);
  }
  __syncthreads();
  for (int p=d; p<289; p+=64){
    int i=p/JJ, j=p-i*JJ;
    const u16* qrow = &qs [(h*JJ+i)*72];
    const u16* krow = &ks_[(h*JJ+j)*72];
    float a=0.f;
    #pragma unroll
    for (int t=0;t<8;t++){
      bf16x8 q8 = *(const bf16x8*)&qrow[t*8];
      bf16x8 k8 = *(const bf16x8*)&krow[t*8];
      #pragma unroll
      for (int e=0;e<8;e++) a += (float)q8[e]*(float)k8[e];
    }
    at[(h*JJ+i)*20 + j] = a*0.125f;
  }
  __syncthreads();
  if (d < JJ){
    float* row = &at[(h*JJ+d)*20];
    f32x4 r0=((f32x4*)row)[0], r1=((f32x4*)row)[1], r2=((f32x4*)row)[2], r3=((f32x4*)row)[3];
    float e16=row[16];
    float rv[JJ]={r0[0],r0[1],r0[2],r0[3],r1[0],r1[1],r1[2],r1[3],
                  r2[0],r2[1],r2[2],r2[3],r3[0],r3[1],r3[2],r3[3],e16};
    float mx=-1e30f;
    #pragma unroll
    for (int j=0;j<JJ;j++) mx=fmaxf(mx,rv[j]);
    float sm=0.f;
    #pragma unroll
    for (int j=0;j<JJ;j++){ rv[j]=__builtin_amdgcn_exp2f((rv[j]-mx)*1.44269504089f); sm+=rv[j]; }
    float inv=1.f/sm;
    #pragma unroll
    for (int j=0;j<JJ;j++) row[j]=rv[j]*inv;
  }
  __syncthreads();
  #pragma unroll
  for (int i=0;i<JJ;i++){
    const float* row = &at[(h*JJ+i)*20];
    f32x4 r0=((const f32x4*)row)[0], r1=((const f32x4*)row)[1],
          r2=((const f32x4*)row)[2], r3=((const f32x4*)row)[3];
    float a = r0[0]*vv[0]+r0[1]*vv[1]+r0[2]*vv[2]+r0[3]*vv[3]
            + r1[0]*vv[4]+r1[1]*vv[5]+r1[2]*vv[6]+r1[3]*vv[7]
            + r2[0]*vv[8]+r2[1]*vv[9]+r2[2]*vv[10]+r2[3]*vv[11]
            + r3[0]*vv[12]+r3[1]*vv[13]+r3[2]*vv[14]+r3[3]*vv[15]
            + row[16]*vv[16];
    sga[((size_t)b*JJ+i)*CC + h*64 + d] = f2bf(a);
  }
}

// ---------------- token MLP: J -> TOK(gelu) -> J, packed-fp32 FMA ----------------
__global__ __launch_bounds__(512) void k_tok(const u16* __restrict__ Hpw,
    const float* __restrict__ w1p, const float* __restrict__ w2p,
    const float* __restrict__ b1, const float* __restrict__ b2,
    u16* __restrict__ h2o){
  __shared__ __align__(16) float w1s[1280], w2s[1280];
  __shared__ float b1s[64], b2s[20];
  const int tid = threadIdx.x;
  for (int i=tid; i<1280; i+=512){ w1s[i]=w1p[i]; w2s[i]=w2p[i]; }
  if (tid<64) b1s[tid]=b1[tid];
  if (tid<20) b2s[tid] = (tid<17) ? b2[tid] : 0.f;
  __syncthreads();

  const int bl = blockIdx.x*2 + (tid>>8);
  const int c0 = tid&255;
  const u16* hp = Hpw + (size_t)bl*JJ*CC;
  float hv0[JJ], hv1[JJ];
  #pragma unroll
  for (int j=0;j<JJ;j++){
    hv0[j]=bf2f(hp[(size_t)j*CC + c0]);
    hv1[j]=bf2f(hp[(size_t)j*CC + c0 + 256]);
  }
  f32x2 h0p[9], h1p[9];
  #pragma unroll
  for (int p=0;p<8;p++){
    h0p[p] = (f32x2){hv0[2*p], hv0[2*p+1]};
    h1p[p] = (f32x2){hv1[2*p], hv1[2*p+1]};
  }
  h0p[8] = (f32x2){hv0[16], 0.f};
  h1p[8] = (f32x2){hv1[16], 0.f};

  f32x2 a20[9], a21[9];
  #pragma unroll
  for (int p=0;p<9;p++){
    f32x2 bb = (f32x2){b2s[2*p], b2s[2*p+1]};
    a20[p]=bb; a21[p]=bb;
  }

  for (int t=0;t<64;t++){
    f32x4 wa = *(const f32x4*)&w1s[t*20];
    f32x4 wb = *(const f32x4*)&w1s[t*20+4];
    f32x4 wc = *(const f32x4*)&w1s[t*20+8];
    f32x4 wd = *(const f32x4*)&w1s[t*20+12];
    float  we = w1s[t*20+16];
    f32x2 wp[9] = {(f32x2){wa[0],wa[1]},(f32x2){wa[2],wa[3]},
                   (f32x2){wb[0],wb[1]},(f32x2){wb[2],wb[3]},
                   (f32x2){wc[0],wc[1]},(f32x2){wc[2],wc[3]},
                   (f32x2){wd[0],wd[1]},(f32x2){wd[2],wd[3]},
                   (f32x2){we,0.f}};
    f32x2 s0 = (f32x2){b1s[t], 0.f};
    f32x2 s1 = s0;
    #pragma unroll
    for (int p=0;p<9;p++){ pkfma(s0, h0p[p], wp[p]); pkfma(s1, h1p[p], wp[p]); }
    float a0 = gelu_f(s0[0] + s0[1]);
    float a1 = gelu_f(s1[0] + s1[1]);
    wa = *(const f32x4*)&w2s[t*20];
    wb = *(const f32x4*)&w2s[t*20+4];
    wc = *(const f32x4*)&w2s[t*20+8];
    wd = *(const f32x4*)&w2s[t*20+12];
    we = w2s[t*20+16];
    f32x2 wq[9] = {(f32x2){wa[0],wa[1]},(f32x2){wa[2],wa[3]},
                   (f32x2){wb[0],wb[1]},(f32x2){wb[2],wb[3]},
                   (f32x2){wc[0],wc[1]},(f32x2){wc[2],wc[3]},
                   (f32x2){wd[0],wd[1]},(f32x2){wd[2],wd[3]},
                   (f32x2){we,0.f}};
    f32x2 a0b = (f32x2){a0,a0};
    f32x2 a1b = (f32x2){a1,a1};
    #pragma unroll
    for (int p=0;p<9;p++){ pkfma(a20[p], a0b, wq[p]); pkfma(a21[p], a1b, wq[p]); }
  }
  u16* ho = h2o + (size_t)bl*JJ*CC;
  #pragma unroll
  for (int j=0;j<JJ;j++){
    ho[(size_t)j*CC + c0]       = f2bf(a20[j>>1][j&1]);
    ho[(size_t)j*CC + c0 + 256] = f2bf(a21[j>>1][j&1]);
  }
}

// ---------------- fuse: GN(gnf)+gelu -> rc ; LN(over C)(rc + x) -> xn ----------------
__global__ __launch_bounds__(512) void k_fuse(const u16* __restrict__ s,
    const float* __restrict__ x, int b0,
    const float* __restrict__ gfw, const float* __restrict__ gfb,
    const float* __restrict__ n2w, const float* __restrict__ n2b,
    u16* __restrict__ rc, u16* __restrict__ xn){
  __shared__ float rS[8][JJ], rQ[8][JJ];
  int b = blockIdx.x, c = threadIdx.x;
  int wave = c>>6, lane = c&63;
  const u16* sp = s + (size_t)b*JJ*CC + c;
  float sv[JJ];
  #pragma unroll
  for (int j=0;j<JJ;j++) sv[j]=bf2f(sp[(size_t)j*CC]);
  float ss=0.f, sq=0.f;
  #pragma unroll
  for (int j=0;j<JJ;j++){ ss+=sv[j]; sq+=sv[j]*sv[j]; }
  for (int off=32; off; off>>=1){ ss += __shfl_xor(ss,off); sq += __shfl_xor(sq,off); }
  float gm = ss*(1.f/1088.f);
  float gr = rsqrtf(sq*(1.f/1088.f) - gm*gm + 1e-5f);
  float gw=gfw[c], gb=gfb[c];
  const float* xp = x + (size_t)(b0+b)*JJ*CC + c;
  u16* rp = rc + (size_t)b*JJ*CC + c;
  float t[JJ];
  #pragma unroll
  for (int j=0;j<JJ;j++){
    float v = gelu_f((sv[j]-gm)*gr*gw + gb);
    rp[(size_t)j*CC] = f2bf(v);
    t[j] = v + xp[(size_t)j*CC];
  }
  #pragma unroll
  for (int j=0;j<JJ;j++){
    float a=t[j], q=a*a;
    for (int off=32; off; off>>=1){ a+=__shfl_xor(a,off); q+=__shfl_xor(q,off); }
    if (lane==0){ rS[wave][j]=a; rQ[wave][j]=q; }
  }
  __syncthreads();
  float wN=n2w[c], bN=n2b[c];
  u16* xo = xn + (size_t)b*JJ*CC + c;
  #pragma unroll
  for (int j=0;j<JJ;j++){
    float S=0.f,Q=0.f;
    #pragma unroll
    for (int w=0;w<8;w++){ S+=rS[w][j]; Q+=rQ[w][j]; }
    float mn=S*(1.f/512.f);
    float r2=rsqrtf(Q*(1.f/512.f)-mn*mn+1e-5f);
    xo[(size_t)j*CC]=f2bf((t[j]-mn)*r2*wN+bN);
  }
}

extern "C" void kernel_launch(void* const* d_in, const int* in_sizes, int n_in,
                              void* d_out, int out_size, void* d_ws, size_t ws_size,
                              hipStream_t stream)
{
  const float* x      = (const float*)d_in[0];
  const float* adj    = (const float*)d_in[1];
  const float* n1w    = (const float*)d_in[2];
  const float* n1b    = (const float*)d_in[3];
  const float* gcn1_w = (const float*)d_in[4];
  const float* gcn1_b = (const float*)d_in[5];
  const float* dw_w   = (const float*)d_in[6];
  const float* dw_b   = (const float*)d_in[7];
  const float* gn1_w  = (const float*)d_in[8];
  const float* gn1_b  = (const float*)d_in[9];
  const float* pw_w   = (const float*)d_in[10];
  const float* pw_b   = (const float*)d_in[11];
  const float* m1w1   = (const float*)d_in[12];
  const float* m1b1   = (const float*)d_in[13];
  const float* m1w2   = (const float*)d_in[14];
  const float* m1b2   = (const float*)d_in[15];
  const float* qkv_w  = (const float*)d_in[16];
  const float* qkv_b  = (const float*)d_in[17];
  const float* proj_w = (const float*)d_in[18];
  const float* proj_b = (const float*)d_in[19];
  const float* gnf_w  = (const float*)d_in[20];
  const float* gnf_b  = (const float*)d_in[21];
  const float* n2w    = (const float*)d_in[22];
  const float* n2b    = (const float*)d_in[23];
  const float* m2w1   = (const float*)d_in[24];
  const float* m2b1   = (const float*)d_in[25];
  const float* m2w2   = (const float*)d_in[26];
  const float* m2b2   = (const float*)d_in[27];
  const float* gcn2_w = (const float*)d_in[28];
  const float* gcn2_b = (const float*)d_in[29];
  float* out = (float*)d_out;

  char* ws = (char*)d_ws;
  const size_t WBYTES = (size_t)3932160*2;
  const size_t TPBYTES = 2560*4;

  const int cands[5] = {4096,2048,1024,512,256};
  int NB = 0;
  for (int ci=0; ci<5; ci++){
    size_t need = WBYTES + TPBYTES + (size_t)cands[ci]*JJ*2*(1536 + 4*512);
    if (need <= ws_size){ NB = cands[ci]; break; }
  }
  if (NB == 0) return;

  u16* wb = (u16*)ws;
  float* w1p = (float*)(ws + WBYTES);
  float* w2p = w1p + 1280;
  char* p = ws + WBYTES + TPBYTES;
  const size_t SZ_BIGc = (size_t)NB*JJ*1536*2;
  const size_t SZTc    = (size_t)NB*JJ*512*2;
  u16* big = (u16*)p;               p += SZ_BIGc;
  u16* t0  = (u16*)p;               p += SZTc;   // xc -> Hpw -> s -> m2
  u16* t1  = (u16*)p;               p += SZTc;   // hgn -> h2 -> rc
  u16* t2  = (u16*)p;               p += SZTc;   // xg -> xn
  u16* t3  = (u16*)p;                            // sga

  u16 *wg1=wb, *wqkv=wb+786432, *wpw=wb+1572864, *wproj=wb+1835008,
      *wm1=wb+2097152, *wm2=wb+2621440, *wg2=wb+3145728;

  k_cvt<<<(786432+255)/256,256,0,stream>>>(gcn1_w,wg1,786432);
  k_cvt<<<(786432+255)/256,256,0,stream>>>(qkv_w,wqkv,786432);
  k_cvt<<<(262144+255)/256,256,0,stream>>>(pw_w,wpw,262144);
  k_cvt<<<(262144+255)/256,256,0,stream>>>(proj_w,wproj,262144);
  k_cvt<<<(524288+255)/256,256,0,stream>>>(m2w1,wm1,524288);
  k_cvt<<<(524288+255)/256,256,0,stream>>>(m2w2,wm2,524288);
  k_cvt<<<(786432+255)/256,256,0,stream>>>(gcn2_w,wg2,786432);
  k_tokprep<<<5,256,0,stream>>>(m1w1,m1w2,w1p,w2p);

  const int M2 = NB*JJ;
  const int MT = M2/128;
  for (int b0 = 0; b0 < BB; b0 += NB){
    k_pre<<<NB,512,0,stream>>>(x,b0,n1w,n1b,dw_w,dw_b,gn1_w,gn1_b, t0/*xc*/, t1/*hgn*/);
    // GCN1
    gemm_r3<0,0><<<MT*12,256,0,stream>>>(t0,wg1,gcn1_b,big,nullptr,nullptr,M2,1536,512,12);
    k_gcn2<0><<<NB/4,512,0,stream>>>(big,adj,t2/*xg*/,nullptr,nullptr,0,nullptr);
    // QKV + attention
    gemm_r3<0,0><<<MT*12,256,0,stream>>>(t0,wqkv,qkv_b,big,nullptr,nullptr,M2,1536,512,12);
    k_attn<<<NB,512,0,stream>>>(big,t3/*sga*/);
    // pw + token MLP  (xc dead -> t0 reused for Hpw)
    gemm_r3<0,0><<<MT*4,256,0,stream>>>(t1,wpw,pw_b,t0/*Hpw*/,nullptr,nullptr,M2,512,512,4);
    k_tok<<<NB/2,512,0,stream>>>(t0,w1p,w2p,m1b1,m1b2,t1/*h2*/);
    // proj + branch merge: s = proj(sga)+b + xg + h2
    gemm_r3<0,1><<<MT*4,256,0,stream>>>(t3,wproj,proj_b,t0/*s*/,t2,t1,M2,512,512,4);
    // GN(gnf)+gelu -> rc ; LN2(rc+x) -> xn
    k_fuse<<<NB,512,0,stream>>>(t0,x,b0,gnf_w,gnf_b,n2w,n2b,t1/*rc*/,t2/*xn*/);
    // MLP2
    gemm_r3<1,0><<<MT*8,256,0,stream>>>(t2,wm1,m2b1,big/*m*/,nullptr,nullptr,M2,1024,512,8);
    gemm_r3<0,0><<<MT*4,256,0,stream>>>(big,wm2,m2b2,t0/*m2*/,nullptr,nullptr,M2,512,1024,4);
    // GCN2
    gemm_r3<0,0><<<MT*12,256,0,stream>>>(t0,wg2,gcn2_b,big/*G2*/,nullptr,nullptr,M2,1536,512,12);
    k_gcn2<1><<<NB/4,512,0,stream>>>(big,adj,nullptr,t1/*rc*/,x,b0,out);
  }
}